// Round 6
// baseline (713.317 us; speedup 1.0000x reference)
//
#include <hip/hip_runtime.h>
#include <hip/hip_cooperative_groups.h>
#include <math.h>

namespace cg = cooperative_groups;

// GCN: h = D^-1/2 (A+I) D^-1/2 (x W) + b, 3 layers + classifier.
// N = 100000 nodes, E = 3.2M edges, feats 128 -> 4 -> 4 -> 2 -> 4.
//
// Round 11: budget closure across r9/r10 (agg-ILP change was perf-neutral)
// says kernel bodies sum to ~229us vs 276-281 measured => ~50us is inter-
// dispatch gaps (9 dispatches x ~6us). Fix: dispatch count 9 -> 4:
//  - histo + ovfc_deg fused into sortb (histosort_kernel, per-bucket ovfC fold)
//  - mm1 + agg1 + agg2 + agg3 fused into ONE cooperative kernel (grid.sync
//    between phases; occupancy-API-sized grid; __launch_bounds__(256,4)).
//    If hipLaunchCooperativeKernel errors (capture unsupported), fall back to
//    the 4 classic dispatches inline. Aggs use the proven round-9 loop form.

#define OVF_CAP 32768
#define NBMAX   512      // max buckets (n <= 131072)
#define CHUNK   4096     // edges per partition block
#define CAPB    11776    // bucket capacity (expected 8192 uniform; 1.44x)

// ---------------- fast path ----------------

__global__ __launch_bounds__(256) void initc_kernel(int* __restrict__ curR, int* __restrict__ curC,
                                                    int* __restrict__ ovfRc, int* __restrict__ ovfCc, int B) {
    int i = blockIdx.x * blockDim.x + threadIdx.x;
    if (i == 0) { *ovfRc = 0; *ovfCc = 0; }
    if (i < B) { curR[i] = i * CAPB; curC[i] = i * CAPB; }
}

// Block-local counting sort per 4096-edge chunk. Side from blockIdx parity:
//   side 0 (R): bin by r>>8, payload ((r&255)<<24)|c into pairs[] (int)
//   side 1 (C): bin by c>>8, payload c&255 into bufC8[] (byte)
__global__ __launch_bounds__(256) void part_kernel(const int* __restrict__ row, const int* __restrict__ col,
                                                   int* __restrict__ curR, int* __restrict__ curC,
                                                   int* __restrict__ pairs, unsigned char* __restrict__ bufC8,
                                                   int* __restrict__ ovfRc, int2* __restrict__ ovfR,
                                                   int* __restrict__ ovfCc, int* __restrict__ ovfC,
                                                   int B, int E) {
    __shared__ int hist[NBMAX];            // counts, then per-bucket cursor
    __shared__ int sA[NBMAX];              // scan ping; after reserve: dBase (gbase - lbase)
    __shared__ int sB[NBMAX];              // scan pong; after reserve: lbase
    __shared__ int sVal[CHUNK];
    __shared__ unsigned short sBk[CHUNK];  // bucket id per sorted slot (0xFFFF = overflow)
    const int t = threadIdx.x;
    const int side = blockIdx.x & 1;
    const long e0 = (long)(blockIdx.x >> 1) * CHUNK;
    int cnt_ch = (int)(E - e0); if (cnt_ch > CHUNK) cnt_ch = CHUNK; if (cnt_ch < 0) cnt_ch = 0;
    const int* __restrict__ key = side == 0 ? row : col;

    // --- histogram ---
    for (int i = t; i < NBMAX; i += 256) hist[i] = 0;
    __syncthreads();
    for (int k = t; k < cnt_ch; k += 256) {
        atomicAdd(&hist[key[e0 + k] >> 8], 1);
    }
    __syncthreads();
    // --- inclusive scan (Hillis-Steele, NBMAX wide) ---
    for (int i = t; i < NBMAX; i += 256) sA[i] = hist[i];
    __syncthreads();
    int* a = sA; int* b = sB;
    for (int off = 1; off < NBMAX; off <<= 1) {
        for (int i = t; i < NBMAX; i += 256)
            b[i] = a[i] + (i >= off ? a[i - off] : 0);
        __syncthreads();
        int* tmp = a; a = b; b = tmp;
    }
    // a[] holds inclusive scan. reserve global runs; b[] <- exclusive local base;
    // a[] <- dBase = gbase - lbase; hist <- cursor.
    int* cur = (side == 0) ? curR : curC;
    for (int i = t; i < NBMAX; i += 256) {
        int cntb = hist[i];
        int lb = a[i] - cntb;
        int g = cntb ? atomicAdd(&cur[i], cntb) : 0;
        b[i] = lb;
        a[i] = g - lb;
        hist[i] = 0;
    }
    __syncthreads();
    // --- sorted placement into LDS ---
    for (int k = t; k < cnt_ch; k += 256) {
        long e = e0 + k;
        int kv = key[e];
        int bk = kv >> 8;
        int rank = atomicAdd(&hist[bk], 1);
        int lpos = b[bk] + rank;
        int gpos = a[bk] + lpos;
        if (gpos < (bk + 1) * CAPB) {
            sVal[lpos] = side == 0 ? (((kv & 255) << 24) | col[e]) : (kv & 255);
            sBk[lpos] = (unsigned short)bk;
        } else {
            sBk[lpos] = 0xFFFFu;
            if (side == 0) {
                int i = atomicAdd(ovfRc, 1);
                if (i < OVF_CAP) ovfR[i] = make_int2(kv, col[e]);
            } else {
                int i = atomicAdd(ovfCc, 1);
                if (i < OVF_CAP) ovfC[i] = kv;
            }
        }
    }
    __syncthreads();
    // --- coalesced dump (gpos = dBase[bk] + local pos) ---
    if (side == 0) {
        for (int k = t; k < cnt_ch; k += 256) {
            int bk = sBk[k];
            if (bk != 0xFFFF) pairs[a[bk] + k] = sVal[k];
        }
    } else {
        for (int k = t; k < cnt_ch; k += 256) {
            int bk = sBk[k];
            if (bk != 0xFFFF) bufC8[a[bk] + k] = (unsigned char)(sVal[k] & 255);
        }
    }
}

// Fused: (a) deg from byte-binned copy (per-bucket LDS histogram + ovfC fold),
// (b) per-bucket full sort by destination row -> CSR rs/re + sorted colidx.
__global__ __launch_bounds__(256) void histosort_kernel(const int* __restrict__ curC, const unsigned char* __restrict__ bufC8,
                                                        const int* __restrict__ ovfCc, const int* __restrict__ ovfC,
                                                        int* __restrict__ deg,
                                                        const int* __restrict__ curR, int* __restrict__ pairs,
                                                        int* __restrict__ rs, int* __restrict__ re, int n) {
    __shared__ int hist[256];
    __shared__ int scn[256];
    __shared__ int sorted[CAPB];
    const int t = threadIdx.x, b = blockIdx.x;
    // ---- deg histogram ----
    hist[t] = 0;
    __syncthreads();
    {
        int baseC = b * CAPB;
        int cntC = curC[b] - baseC; if (cntC > CAPB) cntC = CAPB; if (cntC < 0) cntC = 0;
        for (int k = t; k < cntC; k += 256) atomicAdd(&hist[bufC8[baseC + k]], 1);
        int m = *ovfCc; if (m > OVF_CAP) m = OVF_CAP;
        for (int i = t; i < m; i += 256) {          // normally m == 0
            int c = ovfC[i];
            if ((c >> 8) == b) atomicAdd(&hist[c & 255], 1);
        }
    }
    __syncthreads();
    {
        int v = b * 256 + t;
        if (v < n) deg[v] = hist[t];
    }
    __syncthreads();
    // ---- counting sort of pairs by dest row ----
    const int base = b * CAPB;
    int cnt = curR[b] - base; if (cnt > CAPB) cnt = CAPB; if (cnt < 0) cnt = 0;
    hist[t] = 0;
    __syncthreads();
    for (int k = t; k < cnt; k += 256) atomicAdd(&hist[((unsigned)pairs[base + k]) >> 24], 1);
    __syncthreads();
    int cnt_t = hist[t];
    scn[t] = cnt_t;
    __syncthreads();
    for (int off = 1; off < 256; off <<= 1) {
        int add = (t >= off) ? scn[t - off] : 0;
        __syncthreads();
        scn[t] += add;
        __syncthreads();
    }
    int incl = scn[t], excl = incl - cnt_t;
    int v = b * 256 + t;
    if (v < n) { rs[v] = base + excl; re[v] = base + incl; }
    hist[t] = excl;                  // reuse as cursor
    __syncthreads();
    for (int k = t; k < cnt; k += 256) {
        int p = pairs[base + k];
        int pos = atomicAdd(&hist[((unsigned)p) >> 24], 1);
        sorted[pos] = p & 0xFFFFFF;
    }
    __syncthreads();
    for (int k = t; k < cnt; k += 256) pairs[base + k] = sorted[k];
}

// ---------------- device workers (shared by fused + classic paths) ----------------

__device__ __forceinline__ void mm1_work(int gid, const float* __restrict__ x, const float* __restrict__ W1,
                                         const int* __restrict__ deg, float* __restrict__ dinv,
                                         float4* __restrict__ Td1, int n) {
    int lane = gid & 63;
    int v    = gid >> 6;
    if (v >= n) return;
    float2 xv = ((const float2*)x)[(size_t)v * 64 + lane];
    float4 wa = ((const float4*)W1)[2 * lane];
    float4 wb = ((const float4*)W1)[2 * lane + 1];
    float p0 = xv.x * wa.x + xv.y * wb.x;
    float p1 = xv.x * wa.y + xv.y * wb.y;
    float p2 = xv.x * wa.z + xv.y * wb.z;
    float p3 = xv.x * wa.w + xv.y * wb.w;
#pragma unroll
    for (int off = 32; off > 0; off >>= 1) {
        p0 += __shfl_xor(p0, off);
        p1 += __shfl_xor(p1, off);
        p2 += __shfl_xor(p2, off);
        p3 += __shfl_xor(p3, off);
    }
    if (lane == 0) {
        float d = rsqrtf((float)(deg[v] + 1));
        dinv[v] = d;
        Td1[v] = make_float4(p0 * d, p1 * d, p2 * d, p3 * d);
    }
}

__device__ __forceinline__ void agg1_work(int gid, const int* __restrict__ rs, const int* __restrict__ re,
                                          const int* __restrict__ colidx, const float4* __restrict__ Td1,
                                          const float* __restrict__ dinv,
                                          const int* __restrict__ ovfRc, const int2* __restrict__ ovfR,
                                          const float* __restrict__ b1, const float* __restrict__ W2,
                                          float4* __restrict__ Td2, int n) {
    int v = gid >> 2, sub = gid & 3;
    if (v >= n) return;
    int k = rs[v] + sub;
    const int e = re[v];
    float sx = 0.f, sy = 0.f, sz = 0.f, sw = 0.f;
    for (; k + 28 < e; k += 32) {
        int c0 = colidx[k],      c1 = colidx[k + 4],  c2 = colidx[k + 8],  c3 = colidx[k + 12];
        int c4 = colidx[k + 16], c5 = colidx[k + 20], c6 = colidx[k + 24], c7 = colidx[k + 28];
        float4 a0 = Td1[c0], a1 = Td1[c1], a2 = Td1[c2], a3 = Td1[c3];
        float4 a4 = Td1[c4], a5 = Td1[c5], a6 = Td1[c6], a7 = Td1[c7];
        sx += ((a0.x + a1.x) + (a2.x + a3.x)) + ((a4.x + a5.x) + (a6.x + a7.x));
        sy += ((a0.y + a1.y) + (a2.y + a3.y)) + ((a4.y + a5.y) + (a6.y + a7.y));
        sz += ((a0.z + a1.z) + (a2.z + a3.z)) + ((a4.z + a5.z) + (a6.z + a7.z));
        sw += ((a0.w + a1.w) + (a2.w + a3.w)) + ((a4.w + a5.w) + (a6.w + a7.w));
    }
    for (; k < e; k += 4) {
        float4 a = Td1[colidx[k]];
        sx += a.x; sy += a.y; sz += a.z; sw += a.w;
    }
    sx += __shfl_xor(sx, 1); sy += __shfl_xor(sy, 1); sz += __shfl_xor(sz, 1); sw += __shfl_xor(sw, 1);
    sx += __shfl_xor(sx, 2); sy += __shfl_xor(sy, 2); sz += __shfl_xor(sz, 2); sw += __shfl_xor(sw, 2);
    if (sub != 0) return;
    int m = *ovfRc; if (m > OVF_CAP) m = OVF_CAP;
    for (int i = 0; i < m; ++i) {                    // normally m == 0
        int2 rc = ovfR[i];
        if (rc.x == v) { float4 tv = Td1[rc.y]; sx += tv.x; sy += tv.y; sz += tv.z; sw += tv.w; }
    }
    float4 t0 = Td1[v];                              // self-loop
    sx += t0.x; sy += t0.y; sz += t0.z; sw += t0.w;
    float d = dinv[v];
    float h0 = tanhf(d * sx + b1[0]);
    float h1 = tanhf(d * sy + b1[1]);
    float h2 = tanhf(d * sz + b1[2]);
    float h3 = tanhf(d * sw + b1[3]);
    float4 o;
    o.x = (h0 * W2[0] + h1 * W2[4] + h2 * W2[8]  + h3 * W2[12]) * d;
    o.y = (h0 * W2[1] + h1 * W2[5] + h2 * W2[9]  + h3 * W2[13]) * d;
    o.z = (h0 * W2[2] + h1 * W2[6] + h2 * W2[10] + h3 * W2[14]) * d;
    o.w = (h0 * W2[3] + h1 * W2[7] + h2 * W2[11] + h3 * W2[15]) * d;
    Td2[v] = o;
}

__device__ __forceinline__ void agg2_work(int gid, const int* __restrict__ rs, const int* __restrict__ re,
                                          const int* __restrict__ colidx, const float4* __restrict__ Td2,
                                          const float* __restrict__ dinv,
                                          const int* __restrict__ ovfRc, const int2* __restrict__ ovfR,
                                          const float* __restrict__ b2, const float* __restrict__ W3,
                                          float2* __restrict__ Td3, int n) {
    int v = gid >> 2, sub = gid & 3;
    if (v >= n) return;
    int k = rs[v] + sub;
    const int e = re[v];
    float sx = 0.f, sy = 0.f, sz = 0.f, sw = 0.f;
    for (; k + 28 < e; k += 32) {
        int c0 = colidx[k],      c1 = colidx[k + 4],  c2 = colidx[k + 8],  c3 = colidx[k + 12];
        int c4 = colidx[k + 16], c5 = colidx[k + 20], c6 = colidx[k + 24], c7 = colidx[k + 28];
        float4 a0 = Td2[c0], a1 = Td2[c1], a2 = Td2[c2], a3 = Td2[c3];
        float4 a4 = Td2[c4], a5 = Td2[c5], a6 = Td2[c6], a7 = Td2[c7];
        sx += ((a0.x + a1.x) + (a2.x + a3.x)) + ((a4.x + a5.x) + (a6.x + a7.x));
        sy += ((a0.y + a1.y) + (a2.y + a3.y)) + ((a4.y + a5.y) + (a6.y + a7.y));
        sz += ((a0.z + a1.z) + (a2.z + a3.z)) + ((a4.z + a5.z) + (a6.z + a7.z));
        sw += ((a0.w + a1.w) + (a2.w + a3.w)) + ((a4.w + a5.w) + (a6.w + a7.w));
    }
    for (; k < e; k += 4) {
        float4 a = Td2[colidx[k]];
        sx += a.x; sy += a.y; sz += a.z; sw += a.w;
    }
    sx += __shfl_xor(sx, 1); sy += __shfl_xor(sy, 1); sz += __shfl_xor(sz, 1); sw += __shfl_xor(sw, 1);
    sx += __shfl_xor(sx, 2); sy += __shfl_xor(sy, 2); sz += __shfl_xor(sz, 2); sw += __shfl_xor(sw, 2);
    if (sub != 0) return;
    int m = *ovfRc; if (m > OVF_CAP) m = OVF_CAP;
    for (int i = 0; i < m; ++i) {
        int2 rc = ovfR[i];
        if (rc.x == v) { float4 tv = Td2[rc.y]; sx += tv.x; sy += tv.y; sz += tv.z; sw += tv.w; }
    }
    float4 t0 = Td2[v];
    sx += t0.x; sy += t0.y; sz += t0.z; sw += t0.w;
    float d = dinv[v];
    float h0 = tanhf(d * sx + b2[0]);
    float h1 = tanhf(d * sy + b2[1]);
    float h2 = tanhf(d * sz + b2[2]);
    float h3 = tanhf(d * sw + b2[3]);
    float2 o;
    o.x = (h0 * W3[0] + h1 * W3[2] + h2 * W3[4] + h3 * W3[6]) * d;
    o.y = (h0 * W3[1] + h1 * W3[3] + h2 * W3[5] + h3 * W3[7]) * d;
    Td3[v] = o;
}

__device__ __forceinline__ void agg3_work(int gid, const int* __restrict__ rs, const int* __restrict__ re,
                                          const int* __restrict__ colidx, const float2* __restrict__ Td3,
                                          const float* __restrict__ dinv,
                                          const int* __restrict__ ovfRc, const int2* __restrict__ ovfR,
                                          const float* __restrict__ b3, const float* __restrict__ Wc,
                                          const float* __restrict__ bc, float* __restrict__ out, int n) {
    int v = gid >> 2, sub = gid & 3;
    if (v >= n) return;
    int k = rs[v] + sub;
    const int e = re[v];
    float sx = 0.f, sy = 0.f;
    for (; k + 28 < e; k += 32) {
        int c0 = colidx[k],      c1 = colidx[k + 4],  c2 = colidx[k + 8],  c3 = colidx[k + 12];
        int c4 = colidx[k + 16], c5 = colidx[k + 20], c6 = colidx[k + 24], c7 = colidx[k + 28];
        float2 a0 = Td3[c0], a1 = Td3[c1], a2 = Td3[c2], a3 = Td3[c3];
        float2 a4 = Td3[c4], a5 = Td3[c5], a6 = Td3[c6], a7 = Td3[c7];
        sx += ((a0.x + a1.x) + (a2.x + a3.x)) + ((a4.x + a5.x) + (a6.x + a7.x));
        sy += ((a0.y + a1.y) + (a2.y + a3.y)) + ((a4.y + a5.y) + (a6.y + a7.y));
    }
    for (; k < e; k += 4) {
        float2 a = Td3[colidx[k]];
        sx += a.x; sy += a.y;
    }
    sx += __shfl_xor(sx, 1); sy += __shfl_xor(sy, 1);
    sx += __shfl_xor(sx, 2); sy += __shfl_xor(sy, 2);
    if (sub != 0) return;
    int m = *ovfRc; if (m > OVF_CAP) m = OVF_CAP;
    for (int i = 0; i < m; ++i) {
        int2 rc = ovfR[i];
        if (rc.x == v) { float2 tv = Td3[rc.y]; sx += tv.x; sy += tv.y; }
    }
    float2 t0 = Td3[v];
    sx += t0.x; sy += t0.y;
    float d = dinv[v];
    float h0 = tanhf(d * sx + b3[0]);
    float h1 = tanhf(d * sy + b3[1]);
    float4 o;
    o.x = h0 * Wc[0] + h1 * Wc[4] + bc[0];
    o.y = h0 * Wc[1] + h1 * Wc[5] + bc[1];
    o.z = h0 * Wc[2] + h1 * Wc[6] + bc[2];
    o.w = h0 * Wc[3] + h1 * Wc[7] + bc[3];
    ((float4*)out)[v] = o;
    ((float2*)(out + (size_t)n * 4))[v] = make_float2(h0, h1);
}

// ---------------- classic wrappers (fallback if cooperative launch fails) ----------------

__global__ __launch_bounds__(256) void mm1_kernel(const float* __restrict__ x, const float* __restrict__ W1,
                                                  const int* __restrict__ deg, float* __restrict__ dinv,
                                                  float4* __restrict__ Td1, int n) {
    mm1_work(blockIdx.x * 256 + threadIdx.x, x, W1, deg, dinv, Td1, n);
}
__global__ __launch_bounds__(256) void agg1_kernel(const int* __restrict__ rs, const int* __restrict__ re,
                                                   const int* __restrict__ colidx, const float4* __restrict__ Td1,
                                                   const float* __restrict__ dinv,
                                                   const int* __restrict__ ovfRc, const int2* __restrict__ ovfR,
                                                   const float* __restrict__ b1, const float* __restrict__ W2,
                                                   float4* __restrict__ Td2, int n) {
    agg1_work(blockIdx.x * 256 + threadIdx.x, rs, re, colidx, Td1, dinv, ovfRc, ovfR, b1, W2, Td2, n);
}
__global__ __launch_bounds__(256) void agg2_kernel(const int* __restrict__ rs, const int* __restrict__ re,
                                                   const int* __restrict__ colidx, const float4* __restrict__ Td2,
                                                   const float* __restrict__ dinv,
                                                   const int* __restrict__ ovfRc, const int2* __restrict__ ovfR,
                                                   const float* __restrict__ b2, const float* __restrict__ W3,
                                                   float2* __restrict__ Td3, int n) {
    agg2_work(blockIdx.x * 256 + threadIdx.x, rs, re, colidx, Td2, dinv, ovfRc, ovfR, b2, W3, Td3, n);
}
__global__ __launch_bounds__(256) void agg3_kernel(const int* __restrict__ rs, const int* __restrict__ re,
                                                   const int* __restrict__ colidx, const float2* __restrict__ Td3,
                                                   const float* __restrict__ dinv,
                                                   const int* __restrict__ ovfRc, const int2* __restrict__ ovfR,
                                                   const float* __restrict__ b3, const float* __restrict__ Wc,
                                                   const float* __restrict__ bc, float* __restrict__ out, int n) {
    agg3_work(blockIdx.x * 256 + threadIdx.x, rs, re, colidx, Td3, dinv, ovfRc, ovfR, b3, Wc, bc, out, n);
}

// ---------------- cooperative fused network ----------------

__global__ __launch_bounds__(256, 4) void fused_net(const float* x, const float* W1, const int* deg,
                                                    float* dinv, float4* Td1,
                                                    const int* rs, const int* re, const int* colidx,
                                                    const int* ovfRc, const int2* ovfR,
                                                    const float* b1, const float* W2, float4* Td2,
                                                    const float* b2, const float* W3, float2* Td3,
                                                    const float* b3, const float* Wc, const float* bc,
                                                    float* out, int n) {
    cg::grid_group g = cg::this_grid();
    const int tmm = (n * 64 + 255) / 256;
    for (int blk = blockIdx.x; blk < tmm; blk += gridDim.x)
        mm1_work(blk * 256 + threadIdx.x, x, W1, deg, dinv, Td1, n);
    g.sync();
    const int tag = (n * 4 + 255) / 256;
    for (int blk = blockIdx.x; blk < tag; blk += gridDim.x)
        agg1_work(blk * 256 + threadIdx.x, rs, re, colidx, Td1, dinv, ovfRc, ovfR, b1, W2, Td2, n);
    g.sync();
    for (int blk = blockIdx.x; blk < tag; blk += gridDim.x)
        agg2_work(blk * 256 + threadIdx.x, rs, re, colidx, Td2, dinv, ovfRc, ovfR, b2, W3, Td3, n);
    g.sync();
    for (int blk = blockIdx.x; blk < tag; blk += gridDim.x)
        agg3_work(blk * 256 + threadIdx.x, rs, re, colidx, Td3, dinv, ovfRc, ovfR, b3, Wc, bc, out, n);
}

// ---------------- fallback path (round-2, proven) ----------------

#define ELL_C 64

__global__ __launch_bounds__(256) void zero_kernel(int* __restrict__ p, long count) {
    long i = (long)blockIdx.x * blockDim.x + threadIdx.x;
    if (i < count) p[i] = 0;
}
__global__ __launch_bounds__(256) void build_kernel(const int* __restrict__ row, const int* __restrict__ col,
                                                    int* __restrict__ deg, int* __restrict__ cnt,
                                                    int* __restrict__ slots, int* __restrict__ ovfc,
                                                    int2* __restrict__ ovf, int n, int E) {
    int e = blockIdx.x * blockDim.x + threadIdx.x;
    if (e >= E) return;
    int r = row[e], c = col[e];
    atomicAdd(&deg[c], 1);
    int pos = atomicAdd(&cnt[r], 1);
    if (pos < ELL_C) {
        slots[(size_t)pos * n + r] = c;
    } else {
        int i = atomicAdd(ovfc, 1);
        if (i < OVF_CAP) ovf[i] = make_int2(r, c);
    }
}
__global__ __launch_bounds__(256) void fb_mm1(const float* __restrict__ x, const float* __restrict__ W1,
                                              const int* __restrict__ deg, float* __restrict__ dinv,
                                              float4* __restrict__ A, int n) {
    mm1_work(blockIdx.x * 256 + threadIdx.x, x, W1, deg, dinv, A, n);
}
__global__ __launch_bounds__(256) void ovf4_kernel(const int* __restrict__ ovfc, const int2* __restrict__ ovf,
                                                   const float4* __restrict__ Td, float* __restrict__ B) {
    int e = blockIdx.x * blockDim.x + threadIdx.x;
    int m = *ovfc; if (m > OVF_CAP) m = OVF_CAP;
    if (e >= m) return;
    int2 rc = ovf[e];
    float4 t = Td[rc.y];
    atomicAdd(&B[rc.x * 4 + 0], t.x);
    atomicAdd(&B[rc.x * 4 + 1], t.y);
    atomicAdd(&B[rc.x * 4 + 2], t.z);
    atomicAdd(&B[rc.x * 4 + 3], t.w);
}
__global__ __launch_bounds__(256) void ovf2_kernel(const int* __restrict__ ovfc, const int2* __restrict__ ovf,
                                                   const float2* __restrict__ Td, float* __restrict__ D) {
    int e = blockIdx.x * blockDim.x + threadIdx.x;
    int m = *ovfc; if (m > OVF_CAP) m = OVF_CAP;
    if (e >= m) return;
    int2 rc = ovf[e];
    float2 t = Td[rc.y];
    atomicAdd(&D[rc.x * 2 + 0], t.x);
    atomicAdd(&D[rc.x * 2 + 1], t.y);
}
__global__ __launch_bounds__(256) void agg_node1(const int* __restrict__ cnt, const int* __restrict__ slots,
                                                 const float* __restrict__ dinv, const float4* __restrict__ Td1,
                                                 float4* __restrict__ B, const float* __restrict__ b1,
                                                 const float* __restrict__ W2, float4* __restrict__ Td2, int n) {
    int v = blockIdx.x * blockDim.x + threadIdx.x;
    if (v >= n) return;
    int k = cnt[v]; if (k > ELL_C) k = ELL_C;
    float4 s = B[v];
    for (int j = 0; j < k; ++j) {
        int c = slots[(size_t)j * n + v];
        float4 t = Td1[c];
        s.x += t.x; s.y += t.y; s.z += t.z; s.w += t.w;
    }
    float4 t0 = Td1[v];
    s.x += t0.x; s.y += t0.y; s.z += t0.z; s.w += t0.w;
    float d = dinv[v];
    float h0 = tanhf(d * s.x + b1[0]);
    float h1 = tanhf(d * s.y + b1[1]);
    float h2 = tanhf(d * s.z + b1[2]);
    float h3 = tanhf(d * s.w + b1[3]);
    float4 o;
    o.x = (h0 * W2[0] + h1 * W2[4] + h2 * W2[8]  + h3 * W2[12]) * d;
    o.y = (h0 * W2[1] + h1 * W2[5] + h2 * W2[9]  + h3 * W2[13]) * d;
    o.z = (h0 * W2[2] + h1 * W2[6] + h2 * W2[10] + h3 * W2[14]) * d;
    o.w = (h0 * W2[3] + h1 * W2[7] + h2 * W2[11] + h3 * W2[15]) * d;
    Td2[v] = o;
    B[v] = make_float4(0.f, 0.f, 0.f, 0.f);
}
__global__ __launch_bounds__(256) void agg_node2(const int* __restrict__ cnt, const int* __restrict__ slots,
                                                 const float* __restrict__ dinv, const float4* __restrict__ Td2,
                                                 const float4* __restrict__ B, const float* __restrict__ b2,
                                                 const float* __restrict__ W3, float2* __restrict__ Td3, int n) {
    int v = blockIdx.x * blockDim.x + threadIdx.x;
    if (v >= n) return;
    int k = cnt[v]; if (k > ELL_C) k = ELL_C;
    float4 s = B[v];
    for (int j = 0; j < k; ++j) {
        int c = slots[(size_t)j * n + v];
        float4 t = Td2[c];
        s.x += t.x; s.y += t.y; s.z += t.z; s.w += t.w;
    }
    float4 t0 = Td2[v];
    s.x += t0.x; s.y += t0.y; s.z += t0.z; s.w += t0.w;
    float d = dinv[v];
    float h0 = tanhf(d * s.x + b2[0]);
    float h1 = tanhf(d * s.y + b2[1]);
    float h2 = tanhf(d * s.z + b2[2]);
    float h3 = tanhf(d * s.w + b2[3]);
    float2 o;
    o.x = (h0 * W3[0] + h1 * W3[2] + h2 * W3[4] + h3 * W3[6]) * d;
    o.y = (h0 * W3[1] + h1 * W3[3] + h2 * W3[5] + h3 * W3[7]) * d;
    Td3[v] = o;
}
__global__ __launch_bounds__(256) void agg_node3(const int* __restrict__ cnt, const int* __restrict__ slots,
                                                 const float* __restrict__ dinv, const float2* __restrict__ Td3,
                                                 const float2* __restrict__ D, const float* __restrict__ b3,
                                                 const float* __restrict__ Wc, const float* __restrict__ bc,
                                                 float* __restrict__ out, int n) {
    int v = blockIdx.x * blockDim.x + threadIdx.x;
    if (v >= n) return;
    int k = cnt[v]; if (k > ELL_C) k = ELL_C;
    float2 s = D[v];
    for (int j = 0; j < k; ++j) {
        int c = slots[(size_t)j * n + v];
        float2 t = Td3[c];
        s.x += t.x; s.y += t.y;
    }
    float2 t0 = Td3[v];
    s.x += t0.x; s.y += t0.y;
    float d = dinv[v];
    float h0 = tanhf(d * s.x + b3[0]);
    float h1 = tanhf(d * s.y + b3[1]);
    float4 o;
    o.x = h0 * Wc[0] + h1 * Wc[4] + bc[0];
    o.y = h0 * Wc[1] + h1 * Wc[5] + bc[1];
    o.z = h0 * Wc[2] + h1 * Wc[6] + bc[2];
    o.w = h0 * Wc[3] + h1 * Wc[7] + bc[3];
    ((float4*)out)[v] = o;
    ((float2*)(out + (size_t)n * 4))[v] = make_float2(h0, h1);
}

extern "C" void kernel_launch(void* const* d_in, const int* in_sizes, int n_in,
                              void* d_out, int out_size, void* d_ws, size_t ws_size,
                              hipStream_t stream) {
    const float* x  = (const float*)d_in[0];
    const int*   ei = (const int*)  d_in[1];
    const float* W1 = (const float*)d_in[2];
    const float* b1 = (const float*)d_in[3];
    const float* W2 = (const float*)d_in[4];
    const float* b2 = (const float*)d_in[5];
    const float* W3 = (const float*)d_in[6];
    const float* b3 = (const float*)d_in[7];
    const float* Wc = (const float*)d_in[8];
    const float* bc = (const float*)d_in[9];

    const size_t n = (size_t)(in_sizes[0] / 128);
    const int    E = in_sizes[1] / 2;
    const int* row = ei;       // destinations (segment ids)
    const int* col = ei + E;   // sources (gather)

    const int B     = (int)((n + 255) >> 8);
    const int nb_n  = (int)((n + 255) / 256);
    const int nb_e  = (E + 255) / 256;
    const int nb_mm = (int)((n * 64 + 255) / 256);
    const int nb_ov = OVF_CAP / 256;
    const int nb_p  = (E + CHUNK - 1) / CHUNK;
    const int nb_ag = (int)((n * 4 + 255) / 256);

    int* ws = (int*)d_ws;

    // fast-path layout (ints):
    // pairs B*CAPB (becomes sorted colidx in place) |
    // U = max(ceil(B*CAPB/4) [bufC8], 10*na [Td1 4na, Td2 4na, Td3 2na]) |
    // dinv na | deg na | rs na | re na | curR B | curC B | ovfRc 1 | ovfCc 1
    // (+pad) | ovfR 2*OVF_CAP | ovfC OVF_CAP
    const size_t na = (n + 63) & ~(size_t)63;
    size_t uni = ((size_t)B * CAPB + 3) / 4;
    if (uni < 10 * na) uni = 10 * na;
    size_t need_fast = ((size_t)B * CAPB + uni + 6 * na + 2 * (size_t)B + 4 + 3 * OVF_CAP) * 4 + 64;

    if (ws_size >= need_fast && n <= (1u << 24) && B <= NBMAX) {
        int*   pairs = ws;                             // sorted col indices after histosort
        int*   U     = pairs + (size_t)B * CAPB;
        float* Td1   = (float*)U;                      // 4na
        float* Td2   = Td1 + 4 * na;                   // 4na
        float* Td3   = Td2 + 4 * na;                   // 2na
        unsigned char* bufC8 = (unsigned char*)U;      // dead after histosort (aliases Td)
        float* dinv  = (float*)(U + uni);              // na
        int*   deg   = (int*)(dinv + na);              // na
        int*   rs    = deg + na;                       // na
        int*   re    = rs + na;                        // na
        int*   curR  = re + na;                        // B
        int*   curC  = curR + B;                       // B
        int*   ovfRc = curC + B;                       // 1
        int*   ovfCc = ovfRc + 1;                      // 1
        int2*  ovfR  = (int2*)(ovfCc + 1);
        {   // ensure 8B alignment for int2
            size_t off = (size_t)(ovfCc + 1 - ws);
            if (off & 1) ovfR = (int2*)(ovfCc + 2);
        }
        int*   ovfC  = (int*)(ovfR + OVF_CAP);

        initc_kernel<<<(B + 255) / 256, 256, 0, stream>>>(curR, curC, ovfRc, ovfCc, B);
        part_kernel<<<2 * nb_p, 256, 0, stream>>>(row, col, curR, curC, pairs, bufC8,
                                                  ovfRc, ovfR, ovfCc, ovfC, B, E);
        histosort_kernel<<<B, 256, 0, stream>>>(curC, bufC8, ovfCc, ovfC, deg,
                                                curR, pairs, rs, re, (int)n);
        // bufC8 dead from here; Td region live.

        // cooperative fused mm1 + agg1..3 (grid.sync between phases)
        int dev = 0;
        (void)hipGetDevice(&dev);
        int numCU = 0;
        if (hipDeviceGetAttribute(&numCU, hipDeviceAttributeMultiprocessorCount, dev) != hipSuccess || numCU <= 0)
            numCU = 256;
        int maxBpc = 0;
        if (hipOccupancyMaxActiveBlocksPerMultiprocessor(&maxBpc, fused_net, 256, 0) != hipSuccess || maxBpc < 1)
            maxBpc = 1;
        long cap = (long)maxBpc * (long)numCU;
        long want = (long)nb_ag;
        if (want > cap) want = cap;
        int gsz = (int)(want < 1 ? 1 : want);

        float4* Td1v = (float4*)Td1;
        float4* Td2v = (float4*)Td2;
        float2* Td3v = (float2*)Td3;
        float*  outp = (float*)d_out;
        int ni = (int)n;
        void* kargs[] = {
            (void*)&x, (void*)&W1, (void*)&deg, (void*)&dinv, (void*)&Td1v,
            (void*)&rs, (void*)&re, (void*)&pairs,
            (void*)&ovfRc, (void*)&ovfR,
            (void*)&b1, (void*)&W2, (void*)&Td2v,
            (void*)&b2, (void*)&W3, (void*)&Td3v,
            (void*)&b3, (void*)&Wc, (void*)&bc,
            (void*)&outp, (void*)&ni
        };
        hipError_t ce = hipLaunchCooperativeKernel(fused_net, dim3(gsz), dim3(256), kargs, 0, stream);
        if (ce != hipSuccess) {
            // fallback: classic 4-dispatch chain (proven round-9 path)
            mm1_kernel<<<nb_mm, 256, 0, stream>>>(x, W1, deg, dinv, (float4*)Td1, (int)n);
            agg1_kernel<<<nb_ag, 256, 0, stream>>>(rs, re, pairs, (const float4*)Td1, dinv,
                                                   ovfRc, ovfR, b1, W2, (float4*)Td2, (int)n);
            agg2_kernel<<<nb_ag, 256, 0, stream>>>(rs, re, pairs, (const float4*)Td2, dinv,
                                                   ovfRc, ovfR, b2, W3, (float2*)Td3, (int)n);
            agg3_kernel<<<nb_ag, 256, 0, stream>>>(rs, re, pairs, (const float2*)Td3, dinv,
                                                   ovfRc, ovfR, b3, Wc, bc, (float*)d_out, (int)n);
        }
    } else {
        // fallback: round-2 ELL path (proven)
        float* fws  = (float*)d_ws;
        float* A1   = fws;
        float* A2   = A1 + 4 * n;
        float* C3   = A2 + 4 * n;
        float* Bv   = C3 + 2 * n;
        float* Dv   = Bv + 4 * n;
        float* dinv = Dv + 2 * n;
        int*   cnt  = (int*)(dinv + n);
        int*   deg  = cnt + n;
        int*   ovfc = deg + n;
        int2*  ovf  = (int2*)(ovfc + 4);
        int*   slots = (int*)(ovf + OVF_CAP);

        long zc = (long)(9 * n + 4);
        zero_kernel<<<(int)((zc + 255) / 256), 256, 0, stream>>>((int*)Bv, zc);
        build_kernel<<<nb_e, 256, 0, stream>>>(row, col, deg, cnt, slots, ovfc, ovf, (int)n, E);
        fb_mm1<<<nb_mm, 256, 0, stream>>>(x, W1, deg, dinv, (float4*)A1, (int)n);
        ovf4_kernel<<<nb_ov, 256, 0, stream>>>(ovfc, ovf, (const float4*)A1, Bv);
        agg_node1<<<nb_n, 256, 0, stream>>>(cnt, slots, dinv, (const float4*)A1, (float4*)Bv, b1, W2, (float4*)A2, (int)n);
        ovf4_kernel<<<nb_ov, 256, 0, stream>>>(ovfc, ovf, (const float4*)A2, Bv);
        agg_node2<<<nb_n, 256, 0, stream>>>(cnt, slots, dinv, (const float4*)A2, (const float4*)Bv, b2, W3, (float2*)C3, (int)n);
        ovf2_kernel<<<nb_ov, 256, 0, stream>>>(ovfc, ovf, (const float2*)C3, Dv);
        agg_node3<<<nb_n, 256, 0, stream>>>(cnt, slots, dinv, (const float2*)C3, (const float2*)Dv, b3, Wc, bc, (float*)d_out, (int)n);
    }
}

// Round 7
// 275.804 us; speedup vs baseline: 2.5863x; 2.5863x over previous
//
#include <hip/hip_runtime.h>
#include <math.h>

// GCN: h = D^-1/2 (A+I) D^-1/2 (x W) + b, 3 layers + classifier.
// N = 100000 nodes, E = 3.2M edges, feats 128 -> 4 -> 4 -> 2 -> 4.
//
// Round 12: cooperative grid.sync fusion (r11) was catastrophic (694us,
// VALUBusy 2.3%, HBM 1.1%, VGPR 28 -> phase memory perf destroyed by
// coop build/fencing). REVERTED to classic dispatches. Kept the two
// validated deltas: slim part (30KB LDS, r10) and histosort fusion
// (histo + ovfc_deg + sortb in one kernel, r11-validated). 7 dispatches:
// initc, part (side-split), histosort, mm1, agg1, agg2, agg3.
// Aggs use the round-9 loop form (276.5us best; r10 predicated form worse).

#define OVF_CAP 32768
#define NBMAX   512      // max buckets (n <= 131072)
#define CHUNK   4096     // edges per partition block
#define CAPB    11776    // bucket capacity (expected 8192 uniform; 1.44x)

// ---------------- fast path ----------------

__global__ __launch_bounds__(256) void initc_kernel(int* __restrict__ curR, int* __restrict__ curC,
                                                    int* __restrict__ ovfRc, int* __restrict__ ovfCc, int B) {
    int i = blockIdx.x * blockDim.x + threadIdx.x;
    if (i == 0) { *ovfRc = 0; *ovfCc = 0; }
    if (i < B) { curR[i] = i * CAPB; curC[i] = i * CAPB; }
}

// Block-local counting sort per 4096-edge chunk. Side from blockIdx parity:
//   side 0 (R): bin by r>>8, payload ((r&255)<<24)|c into pairs[] (int)
//   side 1 (C): bin by c>>8, payload c&255 into bufC8[] (byte)
__global__ __launch_bounds__(256) void part_kernel(const int* __restrict__ row, const int* __restrict__ col,
                                                   int* __restrict__ curR, int* __restrict__ curC,
                                                   int* __restrict__ pairs, unsigned char* __restrict__ bufC8,
                                                   int* __restrict__ ovfRc, int2* __restrict__ ovfR,
                                                   int* __restrict__ ovfCc, int* __restrict__ ovfC,
                                                   int B, int E) {
    __shared__ int hist[NBMAX];            // counts, then per-bucket cursor
    __shared__ int sA[NBMAX];              // scan ping; after reserve: dBase (gbase - lbase)
    __shared__ int sB[NBMAX];              // scan pong; after reserve: lbase
    __shared__ int sVal[CHUNK];
    __shared__ unsigned short sBk[CHUNK];  // bucket id per sorted slot (0xFFFF = overflow)
    const int t = threadIdx.x;
    const int side = blockIdx.x & 1;
    const long e0 = (long)(blockIdx.x >> 1) * CHUNK;
    int cnt_ch = (int)(E - e0); if (cnt_ch > CHUNK) cnt_ch = CHUNK; if (cnt_ch < 0) cnt_ch = 0;
    const int* __restrict__ key = side == 0 ? row : col;

    // --- histogram ---
    for (int i = t; i < NBMAX; i += 256) hist[i] = 0;
    __syncthreads();
    for (int k = t; k < cnt_ch; k += 256) {
        atomicAdd(&hist[key[e0 + k] >> 8], 1);
    }
    __syncthreads();
    // --- inclusive scan (Hillis-Steele, NBMAX wide) ---
    for (int i = t; i < NBMAX; i += 256) sA[i] = hist[i];
    __syncthreads();
    int* a = sA; int* b = sB;
    for (int off = 1; off < NBMAX; off <<= 1) {
        for (int i = t; i < NBMAX; i += 256)
            b[i] = a[i] + (i >= off ? a[i - off] : 0);
        __syncthreads();
        int* tmp = a; a = b; b = tmp;
    }
    // a[] holds inclusive scan. reserve global runs; b[] <- exclusive local base;
    // a[] <- dBase = gbase - lbase; hist <- cursor.
    int* cur = (side == 0) ? curR : curC;
    for (int i = t; i < NBMAX; i += 256) {
        int cntb = hist[i];
        int lb = a[i] - cntb;
        int g = cntb ? atomicAdd(&cur[i], cntb) : 0;
        b[i] = lb;
        a[i] = g - lb;
        hist[i] = 0;
    }
    __syncthreads();
    // --- sorted placement into LDS ---
    for (int k = t; k < cnt_ch; k += 256) {
        long e = e0 + k;
        int kv = key[e];
        int bk = kv >> 8;
        int rank = atomicAdd(&hist[bk], 1);
        int lpos = b[bk] + rank;
        int gpos = a[bk] + lpos;
        if (gpos < (bk + 1) * CAPB) {
            sVal[lpos] = side == 0 ? (((kv & 255) << 24) | col[e]) : (kv & 255);
            sBk[lpos] = (unsigned short)bk;
        } else {
            sBk[lpos] = 0xFFFFu;
            if (side == 0) {
                int i = atomicAdd(ovfRc, 1);
                if (i < OVF_CAP) ovfR[i] = make_int2(kv, col[e]);
            } else {
                int i = atomicAdd(ovfCc, 1);
                if (i < OVF_CAP) ovfC[i] = kv;
            }
        }
    }
    __syncthreads();
    // --- coalesced dump (gpos = dBase[bk] + local pos) ---
    if (side == 0) {
        for (int k = t; k < cnt_ch; k += 256) {
            int bk = sBk[k];
            if (bk != 0xFFFF) pairs[a[bk] + k] = sVal[k];
        }
    } else {
        for (int k = t; k < cnt_ch; k += 256) {
            int bk = sBk[k];
            if (bk != 0xFFFF) bufC8[a[bk] + k] = (unsigned char)(sVal[k] & 255);
        }
    }
}

// Fused: (a) deg from byte-binned copy (per-bucket LDS histogram + ovfC fold),
// (b) per-bucket full sort by destination row -> CSR rs/re + sorted colidx.
// Validated on HW in round 11.
__global__ __launch_bounds__(256) void histosort_kernel(const int* __restrict__ curC, const unsigned char* __restrict__ bufC8,
                                                        const int* __restrict__ ovfCc, const int* __restrict__ ovfC,
                                                        int* __restrict__ deg,
                                                        const int* __restrict__ curR, int* __restrict__ pairs,
                                                        int* __restrict__ rs, int* __restrict__ re, int n) {
    __shared__ int hist[256];
    __shared__ int scn[256];
    __shared__ int sorted[CAPB];
    const int t = threadIdx.x, b = blockIdx.x;
    // ---- deg histogram ----
    hist[t] = 0;
    __syncthreads();
    {
        int baseC = b * CAPB;
        int cntC = curC[b] - baseC; if (cntC > CAPB) cntC = CAPB; if (cntC < 0) cntC = 0;
        for (int k = t; k < cntC; k += 256) atomicAdd(&hist[bufC8[baseC + k]], 1);
        int m = *ovfCc; if (m > OVF_CAP) m = OVF_CAP;
        for (int i = t; i < m; i += 256) {          // normally m == 0
            int c = ovfC[i];
            if ((c >> 8) == b) atomicAdd(&hist[c & 255], 1);
        }
    }
    __syncthreads();
    {
        int v = b * 256 + t;
        if (v < n) deg[v] = hist[t];
    }
    __syncthreads();
    // ---- counting sort of pairs by dest row ----
    const int base = b * CAPB;
    int cnt = curR[b] - base; if (cnt > CAPB) cnt = CAPB; if (cnt < 0) cnt = 0;
    hist[t] = 0;
    __syncthreads();
    for (int k = t; k < cnt; k += 256) atomicAdd(&hist[((unsigned)pairs[base + k]) >> 24], 1);
    __syncthreads();
    int cnt_t = hist[t];
    scn[t] = cnt_t;
    __syncthreads();
    for (int off = 1; off < 256; off <<= 1) {
        int add = (t >= off) ? scn[t - off] : 0;
        __syncthreads();
        scn[t] += add;
        __syncthreads();
    }
    int incl = scn[t], excl = incl - cnt_t;
    int v = b * 256 + t;
    if (v < n) { rs[v] = base + excl; re[v] = base + incl; }
    hist[t] = excl;                  // reuse as cursor
    __syncthreads();
    for (int k = t; k < cnt; k += 256) {
        int p = pairs[base + k];
        int pos = atomicAdd(&hist[((unsigned)p) >> 24], 1);
        sorted[pos] = p & 0xFFFFFF;
    }
    __syncthreads();
    for (int k = t; k < cnt; k += 256) pairs[base + k] = sorted[k];
}

// x [n,128] @ W1 [128,4] -> Td1 [n,4], pre-scaled by dinv[v]; also writes dinv.
__global__ __launch_bounds__(256) void mm1_kernel(const float* __restrict__ x, const float* __restrict__ W1,
                                                  const int* __restrict__ deg, float* __restrict__ dinv,
                                                  float4* __restrict__ Td1, int n) {
    int gid  = blockIdx.x * blockDim.x + threadIdx.x;
    int lane = threadIdx.x & 63;
    int v    = gid >> 6;
    if (v >= n) return;
    float2 xv = ((const float2*)x)[(size_t)v * 64 + lane];
    float4 wa = ((const float4*)W1)[2 * lane];
    float4 wb = ((const float4*)W1)[2 * lane + 1];
    float p0 = xv.x * wa.x + xv.y * wb.x;
    float p1 = xv.x * wa.y + xv.y * wb.y;
    float p2 = xv.x * wa.z + xv.y * wb.z;
    float p3 = xv.x * wa.w + xv.y * wb.w;
#pragma unroll
    for (int off = 32; off > 0; off >>= 1) {
        p0 += __shfl_xor(p0, off);
        p1 += __shfl_xor(p1, off);
        p2 += __shfl_xor(p2, off);
        p3 += __shfl_xor(p3, off);
    }
    if (lane == 0) {
        float d = rsqrtf((float)(deg[v] + 1));
        dinv[v] = d;
        Td1[v] = make_float4(p0 * d, p1 * d, p2 * d, p3 * d);
    }
}

// Fused CSR aggregation + layer epilogue, 4 lanes per node, 8 batched
// independent gathers per lane (round-9 proven form). 4-feat in, 4-feat out.
__global__ __launch_bounds__(256) void agg1_kernel(const int* __restrict__ rs, const int* __restrict__ re,
                                                   const int* __restrict__ colidx, const float4* __restrict__ Td1,
                                                   const float* __restrict__ dinv,
                                                   const int* __restrict__ ovfRc, const int2* __restrict__ ovfR,
                                                   const float* __restrict__ b1, const float* __restrict__ W2,
                                                   float4* __restrict__ Td2, int n) {
    int gid = blockIdx.x * 256 + threadIdx.x;
    int v = gid >> 2, sub = gid & 3;
    if (v >= n) return;
    int k = rs[v] + sub;
    const int e = re[v];
    float sx = 0.f, sy = 0.f, sz = 0.f, sw = 0.f;
    for (; k + 28 < e; k += 32) {
        int c0 = colidx[k],      c1 = colidx[k + 4],  c2 = colidx[k + 8],  c3 = colidx[k + 12];
        int c4 = colidx[k + 16], c5 = colidx[k + 20], c6 = colidx[k + 24], c7 = colidx[k + 28];
        float4 a0 = Td1[c0], a1 = Td1[c1], a2 = Td1[c2], a3 = Td1[c3];
        float4 a4 = Td1[c4], a5 = Td1[c5], a6 = Td1[c6], a7 = Td1[c7];
        sx += ((a0.x + a1.x) + (a2.x + a3.x)) + ((a4.x + a5.x) + (a6.x + a7.x));
        sy += ((a0.y + a1.y) + (a2.y + a3.y)) + ((a4.y + a5.y) + (a6.y + a7.y));
        sz += ((a0.z + a1.z) + (a2.z + a3.z)) + ((a4.z + a5.z) + (a6.z + a7.z));
        sw += ((a0.w + a1.w) + (a2.w + a3.w)) + ((a4.w + a5.w) + (a6.w + a7.w));
    }
    for (; k < e; k += 4) {
        float4 a = Td1[colidx[k]];
        sx += a.x; sy += a.y; sz += a.z; sw += a.w;
    }
    sx += __shfl_xor(sx, 1); sy += __shfl_xor(sy, 1); sz += __shfl_xor(sz, 1); sw += __shfl_xor(sw, 1);
    sx += __shfl_xor(sx, 2); sy += __shfl_xor(sy, 2); sz += __shfl_xor(sz, 2); sw += __shfl_xor(sw, 2);
    if (sub != 0) return;
    int m = *ovfRc; if (m > OVF_CAP) m = OVF_CAP;
    for (int i = 0; i < m; ++i) {                    // normally m == 0
        int2 rc = ovfR[i];
        if (rc.x == v) { float4 tv = Td1[rc.y]; sx += tv.x; sy += tv.y; sz += tv.z; sw += tv.w; }
    }
    float4 t0 = Td1[v];                              // self-loop
    sx += t0.x; sy += t0.y; sz += t0.z; sw += t0.w;
    float d = dinv[v];
    float h0 = tanhf(d * sx + b1[0]);
    float h1 = tanhf(d * sy + b1[1]);
    float h2 = tanhf(d * sz + b1[2]);
    float h3 = tanhf(d * sw + b1[3]);
    float4 o;
    o.x = (h0 * W2[0] + h1 * W2[4] + h2 * W2[8]  + h3 * W2[12]) * d;
    o.y = (h0 * W2[1] + h1 * W2[5] + h2 * W2[9]  + h3 * W2[13]) * d;
    o.z = (h0 * W2[2] + h1 * W2[6] + h2 * W2[10] + h3 * W2[14]) * d;
    o.w = (h0 * W2[3] + h1 * W2[7] + h2 * W2[11] + h3 * W2[15]) * d;
    Td2[v] = o;
}

// Layer 2: 4-feat in, 2-feat out.
__global__ __launch_bounds__(256) void agg2_kernel(const int* __restrict__ rs, const int* __restrict__ re,
                                                   const int* __restrict__ colidx, const float4* __restrict__ Td2,
                                                   const float* __restrict__ dinv,
                                                   const int* __restrict__ ovfRc, const int2* __restrict__ ovfR,
                                                   const float* __restrict__ b2, const float* __restrict__ W3,
                                                   float2* __restrict__ Td3, int n) {
    int gid = blockIdx.x * 256 + threadIdx.x;
    int v = gid >> 2, sub = gid & 3;
    if (v >= n) return;
    int k = rs[v] + sub;
    const int e = re[v];
    float sx = 0.f, sy = 0.f, sz = 0.f, sw = 0.f;
    for (; k + 28 < e; k += 32) {
        int c0 = colidx[k],      c1 = colidx[k + 4],  c2 = colidx[k + 8],  c3 = colidx[k + 12];
        int c4 = colidx[k + 16], c5 = colidx[k + 20], c6 = colidx[k + 24], c7 = colidx[k + 28];
        float4 a0 = Td2[c0], a1 = Td2[c1], a2 = Td2[c2], a3 = Td2[c3];
        float4 a4 = Td2[c4], a5 = Td2[c5], a6 = Td2[c6], a7 = Td2[c7];
        sx += ((a0.x + a1.x) + (a2.x + a3.x)) + ((a4.x + a5.x) + (a6.x + a7.x));
        sy += ((a0.y + a1.y) + (a2.y + a3.y)) + ((a4.y + a5.y) + (a6.y + a7.y));
        sz += ((a0.z + a1.z) + (a2.z + a3.z)) + ((a4.z + a5.z) + (a6.z + a7.z));
        sw += ((a0.w + a1.w) + (a2.w + a3.w)) + ((a4.w + a5.w) + (a6.w + a7.w));
    }
    for (; k < e; k += 4) {
        float4 a = Td2[colidx[k]];
        sx += a.x; sy += a.y; sz += a.z; sw += a.w;
    }
    sx += __shfl_xor(sx, 1); sy += __shfl_xor(sy, 1); sz += __shfl_xor(sz, 1); sw += __shfl_xor(sw, 1);
    sx += __shfl_xor(sx, 2); sy += __shfl_xor(sy, 2); sz += __shfl_xor(sz, 2); sw += __shfl_xor(sw, 2);
    if (sub != 0) return;
    int m = *ovfRc; if (m > OVF_CAP) m = OVF_CAP;
    for (int i = 0; i < m; ++i) {
        int2 rc = ovfR[i];
        if (rc.x == v) { float4 tv = Td2[rc.y]; sx += tv.x; sy += tv.y; sz += tv.z; sw += tv.w; }
    }
    float4 t0 = Td2[v];
    sx += t0.x; sy += t0.y; sz += t0.z; sw += t0.w;
    float d = dinv[v];
    float h0 = tanhf(d * sx + b2[0]);
    float h1 = tanhf(d * sy + b2[1]);
    float h2 = tanhf(d * sz + b2[2]);
    float h3 = tanhf(d * sw + b2[3]);
    float2 o;
    o.x = (h0 * W3[0] + h1 * W3[2] + h2 * W3[4] + h3 * W3[6]) * d;
    o.y = (h0 * W3[1] + h1 * W3[3] + h2 * W3[5] + h3 * W3[7]) * d;
    Td3[v] = o;
}

// Layer 3 + classifier: 2-feat in, writes out[0:4n] = logits, out[4n:] = h.
__global__ __launch_bounds__(256) void agg3_kernel(const int* __restrict__ rs, const int* __restrict__ re,
                                                   const int* __restrict__ colidx, const float2* __restrict__ Td3,
                                                   const float* __restrict__ dinv,
                                                   const int* __restrict__ ovfRc, const int2* __restrict__ ovfR,
                                                   const float* __restrict__ b3, const float* __restrict__ Wc,
                                                   const float* __restrict__ bc, float* __restrict__ out, int n) {
    int gid = blockIdx.x * 256 + threadIdx.x;
    int v = gid >> 2, sub = gid & 3;
    if (v >= n) return;
    int k = rs[v] + sub;
    const int e = re[v];
    float sx = 0.f, sy = 0.f;
    for (; k + 28 < e; k += 32) {
        int c0 = colidx[k],      c1 = colidx[k + 4],  c2 = colidx[k + 8],  c3 = colidx[k + 12];
        int c4 = colidx[k + 16], c5 = colidx[k + 20], c6 = colidx[k + 24], c7 = colidx[k + 28];
        float2 a0 = Td3[c0], a1 = Td3[c1], a2 = Td3[c2], a3 = Td3[c3];
        float2 a4 = Td3[c4], a5 = Td3[c5], a6 = Td3[c6], a7 = Td3[c7];
        sx += ((a0.x + a1.x) + (a2.x + a3.x)) + ((a4.x + a5.x) + (a6.x + a7.x));
        sy += ((a0.y + a1.y) + (a2.y + a3.y)) + ((a4.y + a5.y) + (a6.y + a7.y));
    }
    for (; k < e; k += 4) {
        float2 a = Td3[colidx[k]];
        sx += a.x; sy += a.y;
    }
    sx += __shfl_xor(sx, 1); sy += __shfl_xor(sy, 1);
    sx += __shfl_xor(sx, 2); sy += __shfl_xor(sy, 2);
    if (sub != 0) return;
    int m = *ovfRc; if (m > OVF_CAP) m = OVF_CAP;
    for (int i = 0; i < m; ++i) {
        int2 rc = ovfR[i];
        if (rc.x == v) { float2 tv = Td3[rc.y]; sx += tv.x; sy += tv.y; }
    }
    float2 t0 = Td3[v];
    sx += t0.x; sy += t0.y;
    float d = dinv[v];
    float h0 = tanhf(d * sx + b3[0]);
    float h1 = tanhf(d * sy + b3[1]);
    float4 o;
    o.x = h0 * Wc[0] + h1 * Wc[4] + bc[0];
    o.y = h0 * Wc[1] + h1 * Wc[5] + bc[1];
    o.z = h0 * Wc[2] + h1 * Wc[6] + bc[2];
    o.w = h0 * Wc[3] + h1 * Wc[7] + bc[3];
    ((float4*)out)[v] = o;
    ((float2*)(out + (size_t)n * 4))[v] = make_float2(h0, h1);
}

// ---------------- fallback path (round-2, proven) ----------------

#define ELL_C 64

__global__ __launch_bounds__(256) void zero_kernel(int* __restrict__ p, long count) {
    long i = (long)blockIdx.x * blockDim.x + threadIdx.x;
    if (i < count) p[i] = 0;
}
__global__ __launch_bounds__(256) void build_kernel(const int* __restrict__ row, const int* __restrict__ col,
                                                    int* __restrict__ deg, int* __restrict__ cnt,
                                                    int* __restrict__ slots, int* __restrict__ ovfc,
                                                    int2* __restrict__ ovf, int n, int E) {
    int e = blockIdx.x * blockDim.x + threadIdx.x;
    if (e >= E) return;
    int r = row[e], c = col[e];
    atomicAdd(&deg[c], 1);
    int pos = atomicAdd(&cnt[r], 1);
    if (pos < ELL_C) {
        slots[(size_t)pos * n + r] = c;
    } else {
        int i = atomicAdd(ovfc, 1);
        if (i < OVF_CAP) ovf[i] = make_int2(r, c);
    }
}
__global__ __launch_bounds__(256) void fb_mm1(const float* __restrict__ x, const float* __restrict__ W1,
                                              const int* __restrict__ deg, float* __restrict__ dinv,
                                              float4* __restrict__ A, int n) {
    int gid  = blockIdx.x * blockDim.x + threadIdx.x;
    int lane = threadIdx.x & 63;
    int v    = gid >> 6;
    if (v >= n) return;
    float2 xv = ((const float2*)x)[(size_t)v * 64 + lane];
    float4 wa = ((const float4*)W1)[2 * lane];
    float4 wb = ((const float4*)W1)[2 * lane + 1];
    float p0 = xv.x * wa.x + xv.y * wb.x;
    float p1 = xv.x * wa.y + xv.y * wb.y;
    float p2 = xv.x * wa.z + xv.y * wb.z;
    float p3 = xv.x * wa.w + xv.y * wb.w;
#pragma unroll
    for (int off = 32; off > 0; off >>= 1) {
        p0 += __shfl_xor(p0, off); p1 += __shfl_xor(p1, off);
        p2 += __shfl_xor(p2, off); p3 += __shfl_xor(p3, off);
    }
    if (lane == 0) {
        float d = rsqrtf((float)(deg[v] + 1));
        dinv[v] = d;
        A[v] = make_float4(p0 * d, p1 * d, p2 * d, p3 * d);
    }
}
__global__ __launch_bounds__(256) void ovf4_kernel(const int* __restrict__ ovfc, const int2* __restrict__ ovf,
                                                   const float4* __restrict__ Td, float* __restrict__ B) {
    int e = blockIdx.x * blockDim.x + threadIdx.x;
    int m = *ovfc; if (m > OVF_CAP) m = OVF_CAP;
    if (e >= m) return;
    int2 rc = ovf[e];
    float4 t = Td[rc.y];
    atomicAdd(&B[rc.x * 4 + 0], t.x);
    atomicAdd(&B[rc.x * 4 + 1], t.y);
    atomicAdd(&B[rc.x * 4 + 2], t.z);
    atomicAdd(&B[rc.x * 4 + 3], t.w);
}
__global__ __launch_bounds__(256) void ovf2_kernel(const int* __restrict__ ovfc, const int2* __restrict__ ovf,
                                                   const float2* __restrict__ Td, float* __restrict__ D) {
    int e = blockIdx.x * blockDim.x + threadIdx.x;
    int m = *ovfc; if (m > OVF_CAP) m = OVF_CAP;
    if (e >= m) return;
    int2 rc = ovf[e];
    float2 t = Td[rc.y];
    atomicAdd(&D[rc.x * 2 + 0], t.x);
    atomicAdd(&D[rc.x * 2 + 1], t.y);
}
__global__ __launch_bounds__(256) void agg_node1(const int* __restrict__ cnt, const int* __restrict__ slots,
                                                 const float* __restrict__ dinv, const float4* __restrict__ Td1,
                                                 float4* __restrict__ B, const float* __restrict__ b1,
                                                 const float* __restrict__ W2, float4* __restrict__ Td2, int n) {
    int v = blockIdx.x * blockDim.x + threadIdx.x;
    if (v >= n) return;
    int k = cnt[v]; if (k > ELL_C) k = ELL_C;
    float4 s = B[v];
    for (int j = 0; j < k; ++j) {
        int c = slots[(size_t)j * n + v];
        float4 t = Td1[c];
        s.x += t.x; s.y += t.y; s.z += t.z; s.w += t.w;
    }
    float4 t0 = Td1[v];
    s.x += t0.x; s.y += t0.y; s.z += t0.z; s.w += t0.w;
    float d = dinv[v];
    float h0 = tanhf(d * s.x + b1[0]);
    float h1 = tanhf(d * s.y + b1[1]);
    float h2 = tanhf(d * s.z + b1[2]);
    float h3 = tanhf(d * s.w + b1[3]);
    float4 o;
    o.x = (h0 * W2[0] + h1 * W2[4] + h2 * W2[8]  + h3 * W2[12]) * d;
    o.y = (h0 * W2[1] + h1 * W2[5] + h2 * W2[9]  + h3 * W2[13]) * d;
    o.z = (h0 * W2[2] + h1 * W2[6] + h2 * W2[10] + h3 * W2[14]) * d;
    o.w = (h0 * W2[3] + h1 * W2[7] + h2 * W2[11] + h3 * W2[15]) * d;
    Td2[v] = o;
    B[v] = make_float4(0.f, 0.f, 0.f, 0.f);
}
__global__ __launch_bounds__(256) void agg_node2(const int* __restrict__ cnt, const int* __restrict__ slots,
                                                 const float* __restrict__ dinv, const float4* __restrict__ Td2,
                                                 const float4* __restrict__ B, const float* __restrict__ b2,
                                                 const float* __restrict__ W3, float2* __restrict__ Td3, int n) {
    int v = blockIdx.x * blockDim.x + threadIdx.x;
    if (v >= n) return;
    int k = cnt[v]; if (k > ELL_C) k = ELL_C;
    float4 s = B[v];
    for (int j = 0; j < k; ++j) {
        int c = slots[(size_t)j * n + v];
        float4 t = Td2[c];
        s.x += t.x; s.y += t.y; s.z += t.z; s.w += t.w;
    }
    float4 t0 = Td2[v];
    s.x += t0.x; s.y += t0.y; s.z += t0.z; s.w += t0.w;
    float d = dinv[v];
    float h0 = tanhf(d * s.x + b2[0]);
    float h1 = tanhf(d * s.y + b2[1]);
    float h2 = tanhf(d * s.z + b2[2]);
    float h3 = tanhf(d * s.w + b2[3]);
    float2 o;
    o.x = (h0 * W3[0] + h1 * W3[2] + h2 * W3[4] + h3 * W3[6]) * d;
    o.y = (h0 * W3[1] + h1 * W3[3] + h2 * W3[5] + h3 * W3[7]) * d;
    Td3[v] = o;
}
__global__ __launch_bounds__(256) void agg_node3(const int* __restrict__ cnt, const int* __restrict__ slots,
                                                 const float* __restrict__ dinv, const float2* __restrict__ Td3,
                                                 const float2* __restrict__ D, const float* __restrict__ b3,
                                                 const float* __restrict__ Wc, const float* __restrict__ bc,
                                                 float* __restrict__ out, int n) {
    int v = blockIdx.x * blockDim.x + threadIdx.x;
    if (v >= n) return;
    int k = cnt[v]; if (k > ELL_C) k = ELL_C;
    float2 s = D[v];
    for (int j = 0; j < k; ++j) {
        int c = slots[(size_t)j * n + v];
        float2 t = Td3[c];
        s.x += t.x; s.y += t.y;
    }
    float2 t0 = Td3[v];
    s.x += t0.x; s.y += t0.y;
    float d = dinv[v];
    float h0 = tanhf(d * s.x + b3[0]);
    float h1 = tanhf(d * s.y + b3[1]);
    float4 o;
    o.x = h0 * Wc[0] + h1 * Wc[4] + bc[0];
    o.y = h0 * Wc[1] + h1 * Wc[5] + bc[1];
    o.z = h0 * Wc[2] + h1 * Wc[6] + bc[2];
    o.w = h0 * Wc[3] + h1 * Wc[7] + bc[3];
    ((float4*)out)[v] = o;
    ((float2*)(out + (size_t)n * 4))[v] = make_float2(h0, h1);
}

extern "C" void kernel_launch(void* const* d_in, const int* in_sizes, int n_in,
                              void* d_out, int out_size, void* d_ws, size_t ws_size,
                              hipStream_t stream) {
    const float* x  = (const float*)d_in[0];
    const int*   ei = (const int*)  d_in[1];
    const float* W1 = (const float*)d_in[2];
    const float* b1 = (const float*)d_in[3];
    const float* W2 = (const float*)d_in[4];
    const float* b2 = (const float*)d_in[5];
    const float* W3 = (const float*)d_in[6];
    const float* b3 = (const float*)d_in[7];
    const float* Wc = (const float*)d_in[8];
    const float* bc = (const float*)d_in[9];

    const size_t n = (size_t)(in_sizes[0] / 128);
    const int    E = in_sizes[1] / 2;
    const int* row = ei;       // destinations (segment ids)
    const int* col = ei + E;   // sources (gather)

    const int B     = (int)((n + 255) >> 8);
    const int nb_n  = (int)((n + 255) / 256);
    const int nb_e  = (E + 255) / 256;
    const int nb_mm = (int)((n * 64 + 255) / 256);
    const int nb_ov = OVF_CAP / 256;
    const int nb_p  = (E + CHUNK - 1) / CHUNK;
    const int nb_ag = (int)((n * 4 + 255) / 256);

    int* ws = (int*)d_ws;

    // fast-path layout (ints):
    // pairs B*CAPB (becomes sorted colidx in place) |
    // U = max(ceil(B*CAPB/4) [bufC8], 10*na [Td1 4na, Td2 4na, Td3 2na]) |
    // dinv na | deg na | rs na | re na | curR B | curC B | ovfRc 1 | ovfCc 1
    // (+pad) | ovfR 2*OVF_CAP | ovfC OVF_CAP
    const size_t na = (n + 63) & ~(size_t)63;
    size_t uni = ((size_t)B * CAPB + 3) / 4;
    if (uni < 10 * na) uni = 10 * na;
    size_t need_fast = ((size_t)B * CAPB + uni + 6 * na + 2 * (size_t)B + 4 + 3 * OVF_CAP) * 4 + 64;

    if (ws_size >= need_fast && n <= (1u << 24) && B <= NBMAX) {
        int*   pairs = ws;                             // sorted col indices after histosort
        int*   U     = pairs + (size_t)B * CAPB;
        float* Td1   = (float*)U;                      // 4na
        float* Td2   = Td1 + 4 * na;                   // 4na
        float* Td3   = Td2 + 4 * na;                   // 2na
        unsigned char* bufC8 = (unsigned char*)U;      // dead after histosort (aliases Td)
        float* dinv  = (float*)(U + uni);              // na
        int*   deg   = (int*)(dinv + na);              // na
        int*   rs    = deg + na;                       // na
        int*   re    = rs + na;                        // na
        int*   curR  = re + na;                        // B
        int*   curC  = curR + B;                       // B
        int*   ovfRc = curC + B;                       // 1
        int*   ovfCc = ovfRc + 1;                      // 1
        int2*  ovfR  = (int2*)(ovfCc + 1);
        {   // ensure 8B alignment for int2
            size_t off = (size_t)(ovfCc + 1 - ws);
            if (off & 1) ovfR = (int2*)(ovfCc + 2);
        }
        int*   ovfC  = (int*)(ovfR + OVF_CAP);

        initc_kernel<<<(B + 255) / 256, 256, 0, stream>>>(curR, curC, ovfRc, ovfCc, B);
        part_kernel<<<2 * nb_p, 256, 0, stream>>>(row, col, curR, curC, pairs, bufC8,
                                                  ovfRc, ovfR, ovfCc, ovfC, B, E);
        histosort_kernel<<<B, 256, 0, stream>>>(curC, bufC8, ovfCc, ovfC, deg,
                                                curR, pairs, rs, re, (int)n);
        // bufC8 dead from here; Td region live.
        mm1_kernel<<<nb_mm, 256, 0, stream>>>(x, W1, deg, dinv, (float4*)Td1, (int)n);

        agg1_kernel<<<nb_ag, 256, 0, stream>>>(rs, re, pairs, (const float4*)Td1, dinv,
                                               ovfRc, ovfR, b1, W2, (float4*)Td2, (int)n);
        agg2_kernel<<<nb_ag, 256, 0, stream>>>(rs, re, pairs, (const float4*)Td2, dinv,
                                               ovfRc, ovfR, b2, W3, (float2*)Td3, (int)n);
        agg3_kernel<<<nb_ag, 256, 0, stream>>>(rs, re, pairs, (const float2*)Td3, dinv,
                                               ovfRc, ovfR, b3, Wc, bc, (float*)d_out, (int)n);
    } else {
        // fallback: round-2 ELL path (proven)
        float* fws  = (float*)d_ws;
        float* A1   = fws;
        float* A2   = A1 + 4 * n;
        float* C3   = A2 + 4 * n;
        float* Bv   = C3 + 2 * n;
        float* Dv   = Bv + 4 * n;
        float* dinv = Dv + 2 * n;
        int*   cnt  = (int*)(dinv + n);
        int*   deg  = cnt + n;
        int*   ovfc = deg + n;
        int2*  ovf  = (int2*)(ovfc + 4);
        int*   slots = (int*)(ovf + OVF_CAP);

        long zc = (long)(9 * n + 4);
        zero_kernel<<<(int)((zc + 255) / 256), 256, 0, stream>>>((int*)Bv, zc);
        build_kernel<<<nb_e, 256, 0, stream>>>(row, col, deg, cnt, slots, ovfc, ovf, (int)n, E);
        fb_mm1<<<nb_mm, 256, 0, stream>>>(x, W1, deg, dinv, (float4*)A1, (int)n);
        ovf4_kernel<<<nb_ov, 256, 0, stream>>>(ovfc, ovf, (const float4*)A1, Bv);
        agg_node1<<<nb_n, 256, 0, stream>>>(cnt, slots, dinv, (const float4*)A1, (float4*)Bv, b1, W2, (float4*)A2, (int)n);
        ovf4_kernel<<<nb_ov, 256, 0, stream>>>(ovfc, ovf, (const float4*)A2, Bv);
        agg_node2<<<nb_n, 256, 0, stream>>>(cnt, slots, dinv, (const float4*)A2, (const float4*)Bv, b2, W3, (float2*)C3, (int)n);
        ovf2_kernel<<<nb_ov, 256, 0, stream>>>(ovfc, ovf, (const float2*)C3, Dv);
        agg_node3<<<nb_n, 256, 0, stream>>>(cnt, slots, dinv, (const float2*)C3, (const float2*)Dv, b3, Wc, bc, (float*)d_out, (int)n);
    }
}

// Round 8
// 274.563 us; speedup vs baseline: 2.5980x; 1.0045x over previous
//
#include <hip/hip_runtime.h>
#include <math.h>

// GCN: h = D^-1/2 (A+I) D^-1/2 (x W) + b, 3 layers + classifier.
// N = 100000 nodes, E = 3.2M edges, feats 128 -> 4 -> 4 -> 2 -> 4.
//
// Round 13: agg cost (~43us each by budget closure) is invariant across three
// inner-loop forms => not loop-shape-bound. Hypothesis: wave starvation
// (1563 blocks = 6 waves/SIMD, each ~95% stall). Fix: 8 lanes/node (3125
// blocks, saturates 32-wave/CU cap; each lane 1x 4-deep batch). Also initc
// deleted: cursors made RELATIVE (base added at reserve), init is all-zero ->
// one hipMemsetAsync over curR|curC|ovfRc|ovfCc. 6 dispatches + 1 memset.

#define OVF_CAP 32768
#define NBMAX   512      // max buckets (n <= 131072)
#define CHUNK   4096     // edges per partition block
#define CAPB    11776    // bucket capacity (expected 8192 uniform; 1.44x)

// ---------------- fast path ----------------

// Block-local counting sort per 4096-edge chunk. Side from blockIdx parity:
//   side 0 (R): bin by r>>8, payload ((r&255)<<24)|c into pairs[] (int)
//   side 1 (C): bin by c>>8, payload c&255 into bufC8[] (byte)
// curR/curC hold RELATIVE per-bucket cursors (init 0 via memset).
__global__ __launch_bounds__(256) void part_kernel(const int* __restrict__ row, const int* __restrict__ col,
                                                   int* __restrict__ curR, int* __restrict__ curC,
                                                   int* __restrict__ pairs, unsigned char* __restrict__ bufC8,
                                                   int* __restrict__ ovfRc, int2* __restrict__ ovfR,
                                                   int* __restrict__ ovfCc, int* __restrict__ ovfC,
                                                   int B, int E) {
    __shared__ int hist[NBMAX];            // counts, then per-bucket cursor
    __shared__ int sA[NBMAX];              // scan ping; after reserve: dBase (gbase - lbase)
    __shared__ int sB[NBMAX];              // scan pong; after reserve: lbase
    __shared__ int sVal[CHUNK];
    __shared__ unsigned short sBk[CHUNK];  // bucket id per sorted slot (0xFFFF = overflow)
    const int t = threadIdx.x;
    const int side = blockIdx.x & 1;
    const long e0 = (long)(blockIdx.x >> 1) * CHUNK;
    int cnt_ch = (int)(E - e0); if (cnt_ch > CHUNK) cnt_ch = CHUNK; if (cnt_ch < 0) cnt_ch = 0;
    const int* __restrict__ key = side == 0 ? row : col;

    // --- histogram ---
    for (int i = t; i < NBMAX; i += 256) hist[i] = 0;
    __syncthreads();
    for (int k = t; k < cnt_ch; k += 256) {
        atomicAdd(&hist[key[e0 + k] >> 8], 1);
    }
    __syncthreads();
    // --- inclusive scan (Hillis-Steele, NBMAX wide) ---
    for (int i = t; i < NBMAX; i += 256) sA[i] = hist[i];
    __syncthreads();
    int* a = sA; int* b = sB;
    for (int off = 1; off < NBMAX; off <<= 1) {
        for (int i = t; i < NBMAX; i += 256)
            b[i] = a[i] + (i >= off ? a[i - off] : 0);
        __syncthreads();
        int* tmp = a; a = b; b = tmp;
    }
    // a[] holds inclusive scan. reserve global runs; b[] <- exclusive local base;
    // a[] <- dBase = gbase_abs - lbase; hist <- cursor.
    int* cur = (side == 0) ? curR : curC;
    for (int i = t; i < NBMAX; i += 256) {
        int cntb = hist[i];
        int lb = a[i] - cntb;
        int grel = cntb ? atomicAdd(&cur[i], cntb) : 0;
        int g = i * CAPB + grel;         // absolute global base
        b[i] = lb;
        a[i] = g - lb;
        hist[i] = 0;
    }
    __syncthreads();
    // --- sorted placement into LDS ---
    for (int k = t; k < cnt_ch; k += 256) {
        long e = e0 + k;
        int kv = key[e];
        int bk = kv >> 8;
        int rank = atomicAdd(&hist[bk], 1);
        int lpos = b[bk] + rank;
        int gpos = a[bk] + lpos;
        if (gpos < (bk + 1) * CAPB) {
            sVal[lpos] = side == 0 ? (((kv & 255) << 24) | col[e]) : (kv & 255);
            sBk[lpos] = (unsigned short)bk;
        } else {
            sBk[lpos] = 0xFFFFu;
            if (side == 0) {
                int i = atomicAdd(ovfRc, 1);
                if (i < OVF_CAP) ovfR[i] = make_int2(kv, col[e]);
            } else {
                int i = atomicAdd(ovfCc, 1);
                if (i < OVF_CAP) ovfC[i] = kv;
            }
        }
    }
    __syncthreads();
    // --- coalesced dump (gpos = dBase[bk] + local pos) ---
    if (side == 0) {
        for (int k = t; k < cnt_ch; k += 256) {
            int bk = sBk[k];
            if (bk != 0xFFFF) pairs[a[bk] + k] = sVal[k];
        }
    } else {
        for (int k = t; k < cnt_ch; k += 256) {
            int bk = sBk[k];
            if (bk != 0xFFFF) bufC8[a[bk] + k] = (unsigned char)(sVal[k] & 255);
        }
    }
}

// Fused: (a) deg from byte-binned copy (per-bucket LDS histogram + ovfC fold),
// (b) per-bucket full sort by destination row -> CSR rs/re + sorted colidx.
// curR/curC are RELATIVE counts now.
__global__ __launch_bounds__(256) void histosort_kernel(const int* __restrict__ curC, const unsigned char* __restrict__ bufC8,
                                                        const int* __restrict__ ovfCc, const int* __restrict__ ovfC,
                                                        int* __restrict__ deg,
                                                        const int* __restrict__ curR, int* __restrict__ pairs,
                                                        int* __restrict__ rs, int* __restrict__ re, int n) {
    __shared__ int hist[256];
    __shared__ int scn[256];
    __shared__ int sorted[CAPB];
    const int t = threadIdx.x, b = blockIdx.x;
    // ---- deg histogram ----
    hist[t] = 0;
    __syncthreads();
    {
        int baseC = b * CAPB;
        int cntC = curC[b]; if (cntC > CAPB) cntC = CAPB; if (cntC < 0) cntC = 0;
        for (int k = t; k < cntC; k += 256) atomicAdd(&hist[bufC8[baseC + k]], 1);
        int m = *ovfCc; if (m > OVF_CAP) m = OVF_CAP;
        for (int i = t; i < m; i += 256) {          // normally m == 0
            int c = ovfC[i];
            if ((c >> 8) == b) atomicAdd(&hist[c & 255], 1);
        }
    }
    __syncthreads();
    {
        int v = b * 256 + t;
        if (v < n) deg[v] = hist[t];
    }
    __syncthreads();
    // ---- counting sort of pairs by dest row ----
    const int base = b * CAPB;
    int cnt = curR[b]; if (cnt > CAPB) cnt = CAPB; if (cnt < 0) cnt = 0;
    hist[t] = 0;
    __syncthreads();
    for (int k = t; k < cnt; k += 256) atomicAdd(&hist[((unsigned)pairs[base + k]) >> 24], 1);
    __syncthreads();
    int cnt_t = hist[t];
    scn[t] = cnt_t;
    __syncthreads();
    for (int off = 1; off < 256; off <<= 1) {
        int add = (t >= off) ? scn[t - off] : 0;
        __syncthreads();
        scn[t] += add;
        __syncthreads();
    }
    int incl = scn[t], excl = incl - cnt_t;
    int v = b * 256 + t;
    if (v < n) { rs[v] = base + excl; re[v] = base + incl; }
    hist[t] = excl;                  // reuse as cursor
    __syncthreads();
    for (int k = t; k < cnt; k += 256) {
        int p = pairs[base + k];
        int pos = atomicAdd(&hist[((unsigned)p) >> 24], 1);
        sorted[pos] = p & 0xFFFFFF;
    }
    __syncthreads();
    for (int k = t; k < cnt; k += 256) pairs[base + k] = sorted[k];
}

// x [n,128] @ W1 [128,4] -> Td1 [n,4], pre-scaled by dinv[v]; also writes dinv.
__global__ __launch_bounds__(256) void mm1_kernel(const float* __restrict__ x, const float* __restrict__ W1,
                                                  const int* __restrict__ deg, float* __restrict__ dinv,
                                                  float4* __restrict__ Td1, int n) {
    int gid  = blockIdx.x * blockDim.x + threadIdx.x;
    int lane = threadIdx.x & 63;
    int v    = gid >> 6;
    if (v >= n) return;
    float2 xv = ((const float2*)x)[(size_t)v * 64 + lane];
    float4 wa = ((const float4*)W1)[2 * lane];
    float4 wb = ((const float4*)W1)[2 * lane + 1];
    float p0 = xv.x * wa.x + xv.y * wb.x;
    float p1 = xv.x * wa.y + xv.y * wb.y;
    float p2 = xv.x * wa.z + xv.y * wb.z;
    float p3 = xv.x * wa.w + xv.y * wb.w;
#pragma unroll
    for (int off = 32; off > 0; off >>= 1) {
        p0 += __shfl_xor(p0, off);
        p1 += __shfl_xor(p1, off);
        p2 += __shfl_xor(p2, off);
        p3 += __shfl_xor(p3, off);
    }
    if (lane == 0) {
        float d = rsqrtf((float)(deg[v] + 1));
        dinv[v] = d;
        Td1[v] = make_float4(p0 * d, p1 * d, p2 * d, p3 * d);
    }
}

// Fused CSR aggregation + layer epilogue, 8 lanes per node (wave-starvation
// fix: 2x waves, half the per-lane chain; one 4-deep batch covers avg deg 32).
__global__ __launch_bounds__(256) void agg1_kernel(const int* __restrict__ rs, const int* __restrict__ re,
                                                   const int* __restrict__ colidx, const float4* __restrict__ Td1,
                                                   const float* __restrict__ dinv,
                                                   const int* __restrict__ ovfRc, const int2* __restrict__ ovfR,
                                                   const float* __restrict__ b1, const float* __restrict__ W2,
                                                   float4* __restrict__ Td2, int n) {
    int gid = blockIdx.x * 256 + threadIdx.x;
    int v = gid >> 3, sub = gid & 7;
    if (v >= n) return;
    int k = rs[v] + sub;
    const int e = re[v];
    float sx = 0.f, sy = 0.f, sz = 0.f, sw = 0.f;
    for (; k + 24 < e; k += 32) {
        int c0 = colidx[k], c1 = colidx[k + 8], c2 = colidx[k + 16], c3 = colidx[k + 24];
        float4 a0 = Td1[c0], a1 = Td1[c1], a2 = Td1[c2], a3 = Td1[c3];
        sx += (a0.x + a1.x) + (a2.x + a3.x);
        sy += (a0.y + a1.y) + (a2.y + a3.y);
        sz += (a0.z + a1.z) + (a2.z + a3.z);
        sw += (a0.w + a1.w) + (a2.w + a3.w);
    }
    for (; k < e; k += 8) {
        float4 a = Td1[colidx[k]];
        sx += a.x; sy += a.y; sz += a.z; sw += a.w;
    }
    sx += __shfl_xor(sx, 1); sy += __shfl_xor(sy, 1); sz += __shfl_xor(sz, 1); sw += __shfl_xor(sw, 1);
    sx += __shfl_xor(sx, 2); sy += __shfl_xor(sy, 2); sz += __shfl_xor(sz, 2); sw += __shfl_xor(sw, 2);
    sx += __shfl_xor(sx, 4); sy += __shfl_xor(sy, 4); sz += __shfl_xor(sz, 4); sw += __shfl_xor(sw, 4);
    if (sub != 0) return;
    int m = *ovfRc; if (m > OVF_CAP) m = OVF_CAP;
    for (int i = 0; i < m; ++i) {                    // normally m == 0
        int2 rc = ovfR[i];
        if (rc.x == v) { float4 tv = Td1[rc.y]; sx += tv.x; sy += tv.y; sz += tv.z; sw += tv.w; }
    }
    float4 t0 = Td1[v];                              // self-loop
    sx += t0.x; sy += t0.y; sz += t0.z; sw += t0.w;
    float d = dinv[v];
    float h0 = tanhf(d * sx + b1[0]);
    float h1 = tanhf(d * sy + b1[1]);
    float h2 = tanhf(d * sz + b1[2]);
    float h3 = tanhf(d * sw + b1[3]);
    float4 o;
    o.x = (h0 * W2[0] + h1 * W2[4] + h2 * W2[8]  + h3 * W2[12]) * d;
    o.y = (h0 * W2[1] + h1 * W2[5] + h2 * W2[9]  + h3 * W2[13]) * d;
    o.z = (h0 * W2[2] + h1 * W2[6] + h2 * W2[10] + h3 * W2[14]) * d;
    o.w = (h0 * W2[3] + h1 * W2[7] + h2 * W2[11] + h3 * W2[15]) * d;
    Td2[v] = o;
}

// Layer 2: 4-feat in, 2-feat out.
__global__ __launch_bounds__(256) void agg2_kernel(const int* __restrict__ rs, const int* __restrict__ re,
                                                   const int* __restrict__ colidx, const float4* __restrict__ Td2,
                                                   const float* __restrict__ dinv,
                                                   const int* __restrict__ ovfRc, const int2* __restrict__ ovfR,
                                                   const float* __restrict__ b2, const float* __restrict__ W3,
                                                   float2* __restrict__ Td3, int n) {
    int gid = blockIdx.x * 256 + threadIdx.x;
    int v = gid >> 3, sub = gid & 7;
    if (v >= n) return;
    int k = rs[v] + sub;
    const int e = re[v];
    float sx = 0.f, sy = 0.f, sz = 0.f, sw = 0.f;
    for (; k + 24 < e; k += 32) {
        int c0 = colidx[k], c1 = colidx[k + 8], c2 = colidx[k + 16], c3 = colidx[k + 24];
        float4 a0 = Td2[c0], a1 = Td2[c1], a2 = Td2[c2], a3 = Td2[c3];
        sx += (a0.x + a1.x) + (a2.x + a3.x);
        sy += (a0.y + a1.y) + (a2.y + a3.y);
        sz += (a0.z + a1.z) + (a2.z + a3.z);
        sw += (a0.w + a1.w) + (a2.w + a3.w);
    }
    for (; k < e; k += 8) {
        float4 a = Td2[colidx[k]];
        sx += a.x; sy += a.y; sz += a.z; sw += a.w;
    }
    sx += __shfl_xor(sx, 1); sy += __shfl_xor(sy, 1); sz += __shfl_xor(sz, 1); sw += __shfl_xor(sw, 1);
    sx += __shfl_xor(sx, 2); sy += __shfl_xor(sy, 2); sz += __shfl_xor(sz, 2); sw += __shfl_xor(sw, 2);
    sx += __shfl_xor(sx, 4); sy += __shfl_xor(sy, 4); sz += __shfl_xor(sz, 4); sw += __shfl_xor(sw, 4);
    if (sub != 0) return;
    int m = *ovfRc; if (m > OVF_CAP) m = OVF_CAP;
    for (int i = 0; i < m; ++i) {
        int2 rc = ovfR[i];
        if (rc.x == v) { float4 tv = Td2[rc.y]; sx += tv.x; sy += tv.y; sz += tv.z; sw += tv.w; }
    }
    float4 t0 = Td2[v];
    sx += t0.x; sy += t0.y; sz += t0.z; sw += t0.w;
    float d = dinv[v];
    float h0 = tanhf(d * sx + b2[0]);
    float h1 = tanhf(d * sy + b2[1]);
    float h2 = tanhf(d * sz + b2[2]);
    float h3 = tanhf(d * sw + b2[3]);
    float2 o;
    o.x = (h0 * W3[0] + h1 * W3[2] + h2 * W3[4] + h3 * W3[6]) * d;
    o.y = (h0 * W3[1] + h1 * W3[3] + h2 * W3[5] + h3 * W3[7]) * d;
    Td3[v] = o;
}

// Layer 3 + classifier: 2-feat in, writes out[0:4n] = logits, out[4n:] = h.
__global__ __launch_bounds__(256) void agg3_kernel(const int* __restrict__ rs, const int* __restrict__ re,
                                                   const int* __restrict__ colidx, const float2* __restrict__ Td3,
                                                   const float* __restrict__ dinv,
                                                   const int* __restrict__ ovfRc, const int2* __restrict__ ovfR,
                                                   const float* __restrict__ b3, const float* __restrict__ Wc,
                                                   const float* __restrict__ bc, float* __restrict__ out, int n) {
    int gid = blockIdx.x * 256 + threadIdx.x;
    int v = gid >> 3, sub = gid & 7;
    if (v >= n) return;
    int k = rs[v] + sub;
    const int e = re[v];
    float sx = 0.f, sy = 0.f;
    for (; k + 24 < e; k += 32) {
        int c0 = colidx[k], c1 = colidx[k + 8], c2 = colidx[k + 16], c3 = colidx[k + 24];
        float2 a0 = Td3[c0], a1 = Td3[c1], a2 = Td3[c2], a3 = Td3[c3];
        sx += (a0.x + a1.x) + (a2.x + a3.x);
        sy += (a0.y + a1.y) + (a2.y + a3.y);
    }
    for (; k < e; k += 8) {
        float2 a = Td3[colidx[k]];
        sx += a.x; sy += a.y;
    }
    sx += __shfl_xor(sx, 1); sy += __shfl_xor(sy, 1);
    sx += __shfl_xor(sx, 2); sy += __shfl_xor(sy, 2);
    sx += __shfl_xor(sx, 4); sy += __shfl_xor(sy, 4);
    if (sub != 0) return;
    int m = *ovfRc; if (m > OVF_CAP) m = OVF_CAP;
    for (int i = 0; i < m; ++i) {
        int2 rc = ovfR[i];
        if (rc.x == v) { float2 tv = Td3[rc.y]; sx += tv.x; sy += tv.y; }
    }
    float2 t0 = Td3[v];
    sx += t0.x; sy += t0.y;
    float d = dinv[v];
    float h0 = tanhf(d * sx + b3[0]);
    float h1 = tanhf(d * sy + b3[1]);
    float4 o;
    o.x = h0 * Wc[0] + h1 * Wc[4] + bc[0];
    o.y = h0 * Wc[1] + h1 * Wc[5] + bc[1];
    o.z = h0 * Wc[2] + h1 * Wc[6] + bc[2];
    o.w = h0 * Wc[3] + h1 * Wc[7] + bc[3];
    ((float4*)out)[v] = o;
    ((float2*)(out + (size_t)n * 4))[v] = make_float2(h0, h1);
}

// ---------------- fallback path (round-2, proven) ----------------

#define ELL_C 64

__global__ __launch_bounds__(256) void zero_kernel(int* __restrict__ p, long count) {
    long i = (long)blockIdx.x * blockDim.x + threadIdx.x;
    if (i < count) p[i] = 0;
}
__global__ __launch_bounds__(256) void build_kernel(const int* __restrict__ row, const int* __restrict__ col,
                                                    int* __restrict__ deg, int* __restrict__ cnt,
                                                    int* __restrict__ slots, int* __restrict__ ovfc,
                                                    int2* __restrict__ ovf, int n, int E) {
    int e = blockIdx.x * blockDim.x + threadIdx.x;
    if (e >= E) return;
    int r = row[e], c = col[e];
    atomicAdd(&deg[c], 1);
    int pos = atomicAdd(&cnt[r], 1);
    if (pos < ELL_C) {
        slots[(size_t)pos * n + r] = c;
    } else {
        int i = atomicAdd(ovfc, 1);
        if (i < OVF_CAP) ovf[i] = make_int2(r, c);
    }
}
__global__ __launch_bounds__(256) void fb_mm1(const float* __restrict__ x, const float* __restrict__ W1,
                                              const int* __restrict__ deg, float* __restrict__ dinv,
                                              float4* __restrict__ A, int n) {
    int gid  = blockIdx.x * blockDim.x + threadIdx.x;
    int lane = threadIdx.x & 63;
    int v    = gid >> 6;
    if (v >= n) return;
    float2 xv = ((const float2*)x)[(size_t)v * 64 + lane];
    float4 wa = ((const float4*)W1)[2 * lane];
    float4 wb = ((const float4*)W1)[2 * lane + 1];
    float p0 = xv.x * wa.x + xv.y * wb.x;
    float p1 = xv.x * wa.y + xv.y * wb.y;
    float p2 = xv.x * wa.z + xv.y * wb.z;
    float p3 = xv.x * wa.w + xv.y * wb.w;
#pragma unroll
    for (int off = 32; off > 0; off >>= 1) {
        p0 += __shfl_xor(p0, off); p1 += __shfl_xor(p1, off);
        p2 += __shfl_xor(p2, off); p3 += __shfl_xor(p3, off);
    }
    if (lane == 0) {
        float d = rsqrtf((float)(deg[v] + 1));
        dinv[v] = d;
        A[v] = make_float4(p0 * d, p1 * d, p2 * d, p3 * d);
    }
}
__global__ __launch_bounds__(256) void ovf4_kernel(const int* __restrict__ ovfc, const int2* __restrict__ ovf,
                                                   const float4* __restrict__ Td, float* __restrict__ B) {
    int e = blockIdx.x * blockDim.x + threadIdx.x;
    int m = *ovfc; if (m > OVF_CAP) m = OVF_CAP;
    if (e >= m) return;
    int2 rc = ovf[e];
    float4 t = Td[rc.y];
    atomicAdd(&B[rc.x * 4 + 0], t.x);
    atomicAdd(&B[rc.x * 4 + 1], t.y);
    atomicAdd(&B[rc.x * 4 + 2], t.z);
    atomicAdd(&B[rc.x * 4 + 3], t.w);
}
__global__ __launch_bounds__(256) void ovf2_kernel(const int* __restrict__ ovfc, const int2* __restrict__ ovf,
                                                   const float2* __restrict__ Td, float* __restrict__ D) {
    int e = blockIdx.x * blockDim.x + threadIdx.x;
    int m = *ovfc; if (m > OVF_CAP) m = OVF_CAP;
    if (e >= m) return;
    int2 rc = ovf[e];
    float2 t = Td[rc.y];
    atomicAdd(&D[rc.x * 2 + 0], t.x);
    atomicAdd(&D[rc.x * 2 + 1], t.y);
}
__global__ __launch_bounds__(256) void agg_node1(const int* __restrict__ cnt, const int* __restrict__ slots,
                                                 const float* __restrict__ dinv, const float4* __restrict__ Td1,
                                                 float4* __restrict__ B, const float* __restrict__ b1,
                                                 const float* __restrict__ W2, float4* __restrict__ Td2, int n) {
    int v = blockIdx.x * blockDim.x + threadIdx.x;
    if (v >= n) return;
    int k = cnt[v]; if (k > ELL_C) k = ELL_C;
    float4 s = B[v];
    for (int j = 0; j < k; ++j) {
        int c = slots[(size_t)j * n + v];
        float4 t = Td1[c];
        s.x += t.x; s.y += t.y; s.z += t.z; s.w += t.w;
    }
    float4 t0 = Td1[v];
    s.x += t0.x; s.y += t0.y; s.z += t0.z; s.w += t0.w;
    float d = dinv[v];
    float h0 = tanhf(d * s.x + b1[0]);
    float h1 = tanhf(d * s.y + b1[1]);
    float h2 = tanhf(d * s.z + b1[2]);
    float h3 = tanhf(d * s.w + b1[3]);
    float4 o;
    o.x = (h0 * W2[0] + h1 * W2[4] + h2 * W2[8]  + h3 * W2[12]) * d;
    o.y = (h0 * W2[1] + h1 * W2[5] + h2 * W2[9]  + h3 * W2[13]) * d;
    o.z = (h0 * W2[2] + h1 * W2[6] + h2 * W2[10] + h3 * W2[14]) * d;
    o.w = (h0 * W2[3] + h1 * W2[7] + h2 * W2[11] + h3 * W2[15]) * d;
    Td2[v] = o;
    B[v] = make_float4(0.f, 0.f, 0.f, 0.f);
}
__global__ __launch_bounds__(256) void agg_node2(const int* __restrict__ cnt, const int* __restrict__ slots,
                                                 const float* __restrict__ dinv, const float4* __restrict__ Td2,
                                                 const float4* __restrict__ B, const float* __restrict__ b2,
                                                 const float* __restrict__ W3, float2* __restrict__ Td3, int n) {
    int v = blockIdx.x * blockDim.x + threadIdx.x;
    if (v >= n) return;
    int k = cnt[v]; if (k > ELL_C) k = ELL_C;
    float4 s = B[v];
    for (int j = 0; j < k; ++j) {
        int c = slots[(size_t)j * n + v];
        float4 t = Td2[c];
        s.x += t.x; s.y += t.y; s.z += t.z; s.w += t.w;
    }
    float4 t0 = Td2[v];
    s.x += t0.x; s.y += t0.y; s.z += t0.z; s.w += t0.w;
    float d = dinv[v];
    float h0 = tanhf(d * s.x + b2[0]);
    float h1 = tanhf(d * s.y + b2[1]);
    float h2 = tanhf(d * s.z + b2[2]);
    float h3 = tanhf(d * s.w + b2[3]);
    float2 o;
    o.x = (h0 * W3[0] + h1 * W3[2] + h2 * W3[4] + h3 * W3[6]) * d;
    o.y = (h0 * W3[1] + h1 * W3[3] + h2 * W3[5] + h3 * W3[7]) * d;
    Td3[v] = o;
}
__global__ __launch_bounds__(256) void agg_node3(const int* __restrict__ cnt, const int* __restrict__ slots,
                                                 const float* __restrict__ dinv, const float2* __restrict__ Td3,
                                                 const float2* __restrict__ D, const float* __restrict__ b3,
                                                 const float* __restrict__ Wc, const float* __restrict__ bc,
                                                 float* __restrict__ out, int n) {
    int v = blockIdx.x * blockDim.x + threadIdx.x;
    if (v >= n) return;
    int k = cnt[v]; if (k > ELL_C) k = ELL_C;
    float2 s = D[v];
    for (int j = 0; j < k; ++j) {
        int c = slots[(size_t)j * n + v];
        float2 t = Td3[c];
        s.x += t.x; s.y += t.y;
    }
    float2 t0 = Td3[v];
    s.x += t0.x; s.y += t0.y;
    float d = dinv[v];
    float h0 = tanhf(d * s.x + b3[0]);
    float h1 = tanhf(d * s.y + b3[1]);
    float4 o;
    o.x = h0 * Wc[0] + h1 * Wc[4] + bc[0];
    o.y = h0 * Wc[1] + h1 * Wc[5] + bc[1];
    o.z = h0 * Wc[2] + h1 * Wc[6] + bc[2];
    o.w = h0 * Wc[3] + h1 * Wc[7] + bc[3];
    ((float4*)out)[v] = o;
    ((float2*)(out + (size_t)n * 4))[v] = make_float2(h0, h1);
}

extern "C" void kernel_launch(void* const* d_in, const int* in_sizes, int n_in,
                              void* d_out, int out_size, void* d_ws, size_t ws_size,
                              hipStream_t stream) {
    const float* x  = (const float*)d_in[0];
    const int*   ei = (const int*)  d_in[1];
    const float* W1 = (const float*)d_in[2];
    const float* b1 = (const float*)d_in[3];
    const float* W2 = (const float*)d_in[4];
    const float* b2 = (const float*)d_in[5];
    const float* W3 = (const float*)d_in[6];
    const float* b3 = (const float*)d_in[7];
    const float* Wc = (const float*)d_in[8];
    const float* bc = (const float*)d_in[9];

    const size_t n = (size_t)(in_sizes[0] / 128);
    const int    E = in_sizes[1] / 2;
    const int* row = ei;       // destinations (segment ids)
    const int* col = ei + E;   // sources (gather)

    const int B     = (int)((n + 255) >> 8);
    const int nb_n  = (int)((n + 255) / 256);
    const int nb_e  = (E + 255) / 256;
    const int nb_mm = (int)((n * 64 + 255) / 256);
    const int nb_ov = OVF_CAP / 256;
    const int nb_p  = (E + CHUNK - 1) / CHUNK;
    const int nb_ag = (int)((n * 8 + 255) / 256);

    int* ws = (int*)d_ws;

    // fast-path layout (ints):
    // pairs B*CAPB (becomes sorted colidx in place) |
    // U = max(ceil(B*CAPB/4) [bufC8], 10*na [Td1 4na, Td2 4na, Td3 2na]) |
    // dinv na | deg na | rs na | re na | curR B | curC B | ovfRc 1 | ovfCc 1
    // (+pad) | ovfR 2*OVF_CAP | ovfC OVF_CAP
    const size_t na = (n + 63) & ~(size_t)63;
    size_t uni = ((size_t)B * CAPB + 3) / 4;
    if (uni < 10 * na) uni = 10 * na;
    size_t need_fast = ((size_t)B * CAPB + uni + 6 * na + 2 * (size_t)B + 4 + 3 * OVF_CAP) * 4 + 64;

    if (ws_size >= need_fast && n <= (1u << 24) && B <= NBMAX) {
        int*   pairs = ws;                             // sorted col indices after histosort
        int*   U     = pairs + (size_t)B * CAPB;
        float* Td1   = (float*)U;                      // 4na
        float* Td2   = Td1 + 4 * na;                   // 4na
        float* Td3   = Td2 + 4 * na;                   // 2na
        unsigned char* bufC8 = (unsigned char*)U;      // dead after histosort (aliases Td)
        float* dinv  = (float*)(U + uni);              // na
        int*   deg   = (int*)(dinv + na);              // na
        int*   rs    = deg + na;                       // na
        int*   re    = rs + na;                        // na
        int*   curR  = re + na;                        // B
        int*   curC  = curR + B;                       // B
        int*   ovfRc = curC + B;                       // 1
        int*   ovfCc = ovfRc + 1;                      // 1
        int2*  ovfR  = (int2*)(ovfCc + 1);
        {   // ensure 8B alignment for int2
            size_t off = (size_t)(ovfCc + 1 - ws);
            if (off & 1) ovfR = (int2*)(ovfCc + 2);
        }
        int*   ovfC  = (int*)(ovfR + OVF_CAP);

        // init: relative cursors + overflow counters are all zeros (contiguous).
        hipMemsetAsync(curR, 0, (size_t)(2 * B + 4) * sizeof(int), stream);
        part_kernel<<<2 * nb_p, 256, 0, stream>>>(row, col, curR, curC, pairs, bufC8,
                                                  ovfRc, ovfR, ovfCc, ovfC, B, E);
        histosort_kernel<<<B, 256, 0, stream>>>(curC, bufC8, ovfCc, ovfC, deg,
                                                curR, pairs, rs, re, (int)n);
        // bufC8 dead from here; Td region live.
        mm1_kernel<<<nb_mm, 256, 0, stream>>>(x, W1, deg, dinv, (float4*)Td1, (int)n);

        agg1_kernel<<<nb_ag, 256, 0, stream>>>(rs, re, pairs, (const float4*)Td1, dinv,
                                               ovfRc, ovfR, b1, W2, (float4*)Td2, (int)n);
        agg2_kernel<<<nb_ag, 256, 0, stream>>>(rs, re, pairs, (const float4*)Td2, dinv,
                                               ovfRc, ovfR, b2, W3, (float2*)Td3, (int)n);
        agg3_kernel<<<nb_ag, 256, 0, stream>>>(rs, re, pairs, (const float2*)Td3, dinv,
                                               ovfRc, ovfR, b3, Wc, bc, (float*)d_out, (int)n);
    } else {
        // fallback: round-2 ELL path (proven)
        float* fws  = (float*)d_ws;
        float* A1   = fws;
        float* A2   = A1 + 4 * n;
        float* C3   = A2 + 4 * n;
        float* Bv   = C3 + 2 * n;
        float* Dv   = Bv + 4 * n;
        float* dinv = Dv + 2 * n;
        int*   cnt  = (int*)(dinv + n);
        int*   deg  = cnt + n;
        int*   ovfc = deg + n;
        int2*  ovf  = (int2*)(ovfc + 4);
        int*   slots = (int*)(ovf + OVF_CAP);

        long zc = (long)(9 * n + 4);
        zero_kernel<<<(int)((zc + 255) / 256), 256, 0, stream>>>((int*)Bv, zc);
        build_kernel<<<nb_e, 256, 0, stream>>>(row, col, deg, cnt, slots, ovfc, ovf, (int)n, E);
        fb_mm1<<<nb_mm, 256, 0, stream>>>(x, W1, deg, dinv, (float4*)A1, (int)n);
        ovf4_kernel<<<nb_ov, 256, 0, stream>>>(ovfc, ovf, (const float4*)A1, Bv);
        agg_node1<<<nb_n, 256, 0, stream>>>(cnt, slots, dinv, (const float4*)A1, (float4*)Bv, b1, W2, (float4*)A2, (int)n);
        ovf4_kernel<<<nb_ov, 256, 0, stream>>>(ovfc, ovf, (const float4*)A2, Bv);
        agg_node2<<<nb_n, 256, 0, stream>>>(cnt, slots, dinv, (const float4*)A2, (const float4*)Bv, b2, W3, (float2*)C3, (int)n);
        ovf2_kernel<<<nb_ov, 256, 0, stream>>>(ovfc, ovf, (const float2*)C3, Dv);
        agg_node3<<<nb_n, 256, 0, stream>>>(cnt, slots, dinv, (const float2*)C3, (const float2*)Dv, b3, Wc, bc, (float*)d_out, (int)n);
    }
}